// Round 1
// baseline (1566.571 us; speedup 1.0000x reference)
//
#include <hip/hip_runtime.h>
#include <math.h>

#define NN 16384
#define EE 131072
#define ZZ 128
#define HH 8

__device__ __forceinline__ float silu_f(float x) { return x / (1.0f + __expf(-x)); }

// order-preserving float->uint encoding for atomicMax
__device__ __forceinline__ unsigned fenc(float x) {
    unsigned b = __float_as_uint(x);
    return (b & 0x80000000u) ? ~b : (b | 0x80000000u);
}
__device__ __forceinline__ float fdec(unsigned e) {
    unsigned b = (e & 0x80000000u) ? (e & 0x7FFFFFFFu) : ~e;
    return __uint_as_float(b);
}

// C[M x P] = act(A[M x 128] @ W[128 x P] + bias), tile 64 rows x 128 cols.
// A row stride = 128 (contiguous). grid = (M/64, P/128). block = 256.
// ACT: 0 = none, 1 = silu
template <int ACT>
__global__ __launch_bounds__(256) void gemm_k128(
    const float* __restrict__ A, const float* __restrict__ W,
    const float* __restrict__ bias, float* __restrict__ C, int P)
{
    __shared__ float As[64 * 128];
    const int row0 = blockIdx.x * 64;
    const int cg = blockIdx.y * 128;
    const int t = threadIdx.x;
    {
        const float4* Ag = (const float4*)(A + (size_t)row0 * 128);
        float4* As4 = (float4*)As;
#pragma unroll
        for (int i = 0; i < 8; ++i) As4[t + i * 256] = Ag[t + i * 256];
    }
    __syncthreads();
    const int c = (t & 31) * 4;   // 0..127
    const int r0 = (t >> 5) * 8;  // 0..56
    float acc[8][4];
#pragma unroll
    for (int r = 0; r < 8; ++r) { acc[r][0] = 0.f; acc[r][1] = 0.f; acc[r][2] = 0.f; acc[r][3] = 0.f; }
    const float* Wp = W + cg + c;
#pragma unroll 4
    for (int kk = 0; kk < 128; ++kk) {
        const float4 w = *(const float4*)(Wp + (size_t)kk * P);
#pragma unroll
        for (int r = 0; r < 8; ++r) {
            const float a = As[(r0 + r) * 128 + kk];  // wave-broadcast LDS read
            acc[r][0] = fmaf(a, w.x, acc[r][0]);
            acc[r][1] = fmaf(a, w.y, acc[r][1]);
            acc[r][2] = fmaf(a, w.z, acc[r][2]);
            acc[r][3] = fmaf(a, w.w, acc[r][3]);
        }
    }
    float bx = 0.f, by = 0.f, bz = 0.f, bw = 0.f;
    if (bias) { const float4 b4 = *(const float4*)(bias + cg + c); bx = b4.x; by = b4.y; bz = b4.z; bw = b4.w; }
#pragma unroll
    for (int r = 0; r < 8; ++r) {
        float4 o;
        o.x = acc[r][0] + bx; o.y = acc[r][1] + by; o.z = acc[r][2] + bz; o.w = acc[r][3] + bw;
        if (ACT == 1) { o.x = silu_f(o.x); o.y = silu_f(o.y); o.z = silu_f(o.z); o.w = silu_f(o.w); }
        *(float4*)(C + (size_t)(row0 + r0 + r) * P + cg + c) = o;
    }
}

// logits[e][h] = sum_zh q[dst][h*16+zh] * k[src][h*16+zh] * r_attn[e][h*16+zh]
// + atomicMax of encoded logit into mEnc[dst*8+h]
__global__ __launch_bounds__(256) void logits_max_kernel(
    const float* __restrict__ q, const float* __restrict__ k,
    const float* __restrict__ ra, const int* __restrict__ src,
    const int* __restrict__ dst, float* __restrict__ lg,
    unsigned* __restrict__ mEnc)
{
    const int idx = blockIdx.x * 256 + threadIdx.x;  // over E*8
    const int e = idx >> 3, h = idx & 7;
    const int s = src[e], d = dst[e];
    const float4* qp = (const float4*)(q + (size_t)d * 128 + h * 16);
    const float4* kp = (const float4*)(k + (size_t)s * 128 + h * 16);
    const float4* rp = (const float4*)(ra + (size_t)e * 128 + h * 16);
    float sum = 0.f;
#pragma unroll
    for (int i = 0; i < 4; ++i) {
        const float4 a = qp[i], b = kp[i], r = rp[i];
        sum += a.x * b.x * r.x + a.y * b.y * r.y + a.z * b.z * r.z + a.w * b.w * r.w;
    }
    lg[idx] = sum;
    atomicMax(&mEnc[d * 8 + h], fenc(sum));
}

__global__ __launch_bounds__(256) void exp_den_kernel(
    const int* __restrict__ dst, const unsigned* __restrict__ mEnc,
    float* __restrict__ lg, float* __restrict__ den)
{
    const int idx = blockIdx.x * 256 + threadIdx.x;
    const int e = idx >> 3, h = idx & 7;
    const int d = dst[e];
    const float m = fdec(mEnc[d * 8 + h]);
    const float ex = __expf(lg[idx] - m);
    lg[idx] = ex;
    atomicAdd(&den[d * 8 + h], ex);
}

__global__ __launch_bounds__(256) void attn_fin_kernel(
    const int* __restrict__ dst, const float* __restrict__ den,
    const float* __restrict__ nee, float* __restrict__ lg)
{
    const int idx = blockIdx.x * 256 + threadIdx.x;
    const int e = idx >> 3, h = idx & 7;
    const int d = dst[e];
    lg[idx] = lg[idx] / den[d * 8 + h] * sqrtf(nee[e]) * 0.08838834764831845f; // 1/sqrt(128)
}

// Fused: r_ij = emb @ W_re + b_re (E x 384 GEMM), epilogue builds
// x_ij = cut * attn[h(c)] * val3[src][c] * x3[src][c] * r_ij, then scatters
// o_s into h_out and dmu (o_d*ev_l + o_t*mu[src][l]) into mu_out via atomics.
__global__ __launch_bounds__(256) void combine_scatter_kernel(
    const float* __restrict__ emb, const float* __restrict__ Wre,
    const float* __restrict__ bre, const float* __restrict__ attn,
    const float* __restrict__ x3, const float* __restrict__ val3,
    const float* __restrict__ ew, const float* __restrict__ ev,
    const float* __restrict__ mu, const int* __restrict__ src,
    const int* __restrict__ dst, float* __restrict__ h_out,
    float* __restrict__ mu_out)
{
    __shared__ float Es[64 * 128];
    const int e0 = blockIdx.x * 64;
    const int t = threadIdx.x;
    {
        const float4* Eg = (const float4*)(emb + (size_t)e0 * 128);
        float4* Es4 = (float4*)Es;
#pragma unroll
        for (int i = 0; i < 8; ++i) Es4[t + i * 256] = Eg[t + i * 256];
    }
    __syncthreads();
    const int c = (t & 31) * 4;
    const int r0 = (t >> 5) * 8;
    float acc0[8][4] = {}, acc1[8][4] = {}, acc2[8][4] = {};
    const float* W0 = Wre + c;
#pragma unroll 2
    for (int kk = 0; kk < 128; ++kk) {
        const float* Wr = W0 + kk * 384;
        const float4 w0 = *(const float4*)(Wr);
        const float4 w1 = *(const float4*)(Wr + 128);
        const float4 w2 = *(const float4*)(Wr + 256);
#pragma unroll
        for (int r = 0; r < 8; ++r) {
            const float a = Es[(r0 + r) * 128 + kk];
            acc0[r][0] = fmaf(a, w0.x, acc0[r][0]); acc0[r][1] = fmaf(a, w0.y, acc0[r][1]);
            acc0[r][2] = fmaf(a, w0.z, acc0[r][2]); acc0[r][3] = fmaf(a, w0.w, acc0[r][3]);
            acc1[r][0] = fmaf(a, w1.x, acc1[r][0]); acc1[r][1] = fmaf(a, w1.y, acc1[r][1]);
            acc1[r][2] = fmaf(a, w1.z, acc1[r][2]); acc1[r][3] = fmaf(a, w1.w, acc1[r][3]);
            acc2[r][0] = fmaf(a, w2.x, acc2[r][0]); acc2[r][1] = fmaf(a, w2.y, acc2[r][1]);
            acc2[r][2] = fmaf(a, w2.z, acc2[r][2]); acc2[r][3] = fmaf(a, w2.w, acc2[r][3]);
        }
    }
    const float4 b0 = *(const float4*)(bre + c);
    const float4 b1 = *(const float4*)(bre + 128 + c);
    const float4 b2 = *(const float4*)(bre + 256 + c);
    const int h0 = c / 48, h1 = (128 + c) / 48, h2 = (256 + c) / 48;  // quads never straddle head bounds
#pragma unroll
    for (int r = 0; r < 8; ++r) {
        const int e = e0 + r0 + r;
        const int s = src[e], d = dst[e];
        const float w = ew[e];
        const float cut = (w < 5.0f) ? 0.5f * (cosf(w * 0.62831853071795864f) + 1.0f) : 0.0f;
        const float* ap = attn + (size_t)e * 8;
        const float a0 = ap[h0] * cut, a1 = ap[h1] * cut, a2 = ap[h2] * cut;
        const float* v3p = val3 + (size_t)s * 384;
        const float* x3p = x3 + (size_t)s * 384;
        const float4 v0 = *(const float4*)(v3p + c);
        const float4 xx0 = *(const float4*)(x3p + c);
        const float4 v1 = *(const float4*)(v3p + 128 + c);
        const float4 xx1 = *(const float4*)(x3p + 128 + c);
        const float4 v2 = *(const float4*)(v3p + 256 + c);
        const float4 xx2 = *(const float4*)(x3p + 256 + c);
        float os[4], od[4], ot[4];
        os[0] = (acc0[r][0] + b0.x) * a0 * v0.x * xx0.x;
        os[1] = (acc0[r][1] + b0.y) * a0 * v0.y * xx0.y;
        os[2] = (acc0[r][2] + b0.z) * a0 * v0.z * xx0.z;
        os[3] = (acc0[r][3] + b0.w) * a0 * v0.w * xx0.w;
        od[0] = (acc1[r][0] + b1.x) * a1 * v1.x * xx1.x;
        od[1] = (acc1[r][1] + b1.y) * a1 * v1.y * xx1.y;
        od[2] = (acc1[r][2] + b1.z) * a1 * v1.z * xx1.z;
        od[3] = (acc1[r][3] + b1.w) * a1 * v1.w * xx1.w;
        ot[0] = (acc2[r][0] + b2.x) * a2 * v2.x * xx2.x;
        ot[1] = (acc2[r][1] + b2.y) * a2 * v2.y * xx2.y;
        ot[2] = (acc2[r][2] + b2.z) * a2 * v2.z * xx2.z;
        ot[3] = (acc2[r][3] + b2.w) * a2 * v2.w * xx2.w;
        float* hp = h_out + (size_t)d * 128 + c;
        atomicAdd(hp + 0, os[0]); atomicAdd(hp + 1, os[1]);
        atomicAdd(hp + 2, os[2]); atomicAdd(hp + 3, os[3]);
        const float evl[3] = { ev[e * 3 + 0], ev[e * 3 + 1], ev[e * 3 + 2] };
        const float* msp = mu + (size_t)s * 384;
        float* mdp = mu_out + (size_t)d * 384;
#pragma unroll
        for (int l = 0; l < 3; ++l) {
            const float4 m4 = *(const float4*)(msp + l * 128 + c);
            atomicAdd(mdp + l * 128 + c + 0, od[0] * evl[l] + ot[0] * m4.x);
            atomicAdd(mdp + l * 128 + c + 1, od[1] * evl[l] + ot[1] * m4.y);
            atomicAdd(mdp + l * 128 + c + 2, od[2] * evl[l] + ot[2] * m4.z);
            atomicAdd(mdp + l * 128 + c + 3, od[3] * evl[l] + ot[3] * m4.w);
        }
    }
}

// w1d[e][z] = sum_l w1[dst][l][z]*ev[l]; w2d[e][z] = sum_l w2[src][l][z]*ev[l]
__global__ __launch_bounds__(256) void wd_kernel(
    const float* __restrict__ w1, const float* __restrict__ w2,
    const float* __restrict__ ev, const int* __restrict__ src,
    const int* __restrict__ dst, float* __restrict__ w1d, float* __restrict__ w2d)
{
    const int idx = blockIdx.x * 256 + threadIdx.x;  // over E*32
    const int e = idx >> 5, zq = (idx & 31) * 4;
    const int s = src[e], d = dst[e];
    const float e0 = ev[e * 3 + 0], e1 = ev[e * 3 + 1], e2 = ev[e * 3 + 2];
    const float* p1 = w1 + (size_t)d * 384 + zq;
    const float* p2 = w2 + (size_t)s * 384 + zq;
    const float4 a0 = *(const float4*)(p1), a1 = *(const float4*)(p1 + 128), a2 = *(const float4*)(p1 + 256);
    const float4 c0 = *(const float4*)(p2), c1 = *(const float4*)(p2 + 128), c2 = *(const float4*)(p2 + 256);
    float4 o1, o2;
    o1.x = e0 * a0.x + e1 * a1.x + e2 * a2.x;
    o1.y = e0 * a0.y + e1 * a1.y + e2 * a2.y;
    o1.z = e0 * a0.z + e1 * a1.z + e2 * a2.z;
    o1.w = e0 * a0.w + e1 * a1.w + e2 * a2.w;
    o2.x = e0 * c0.x + e1 * c1.x + e2 * c2.x;
    o2.y = e0 * c0.y + e1 * c1.y + e2 * c2.y;
    o2.z = e0 * c0.z + e1 * c1.z + e2 * c2.z;
    o2.w = e0 * c0.w + e1 * c1.w + e2 * c2.w;
    *(float4*)(w1d + (size_t)e * 128 + zq) = o1;
    *(float4*)(w2d + (size_t)e * 128 + zq) = o2;
}

// df = emb + f_up * tanh((w1d*w2d) @ W_lin + b_lin)
__global__ __launch_bounds__(256) void wdot_df_kernel(
    const float* __restrict__ w1d, const float* __restrict__ w2d,
    const float* __restrict__ Wl, const float* __restrict__ bl,
    const float* __restrict__ emb, const float* __restrict__ f_up,
    float* __restrict__ df)
{
    __shared__ float As[64 * 128];
    const int row0 = blockIdx.x * 64;
    const int t = threadIdx.x;
    {
        const float4* A1 = (const float4*)(w1d + (size_t)row0 * 128);
        const float4* A2 = (const float4*)(w2d + (size_t)row0 * 128);
        float4* As4 = (float4*)As;
#pragma unroll
        for (int i = 0; i < 8; ++i) {
            const float4 a = A1[t + i * 256];
            const float4 b = A2[t + i * 256];
            float4 p; p.x = a.x * b.x; p.y = a.y * b.y; p.z = a.z * b.z; p.w = a.w * b.w;
            As4[t + i * 256] = p;
        }
    }
    __syncthreads();
    const int c = (t & 31) * 4;
    const int r0 = (t >> 5) * 8;
    float acc[8][4];
#pragma unroll
    for (int r = 0; r < 8; ++r) { acc[r][0] = 0.f; acc[r][1] = 0.f; acc[r][2] = 0.f; acc[r][3] = 0.f; }
    const float* Wp = Wl + c;
#pragma unroll 4
    for (int kk = 0; kk < 128; ++kk) {
        const float4 w = *(const float4*)(Wp + (size_t)kk * 128);
#pragma unroll
        for (int r = 0; r < 8; ++r) {
            const float a = As[(r0 + r) * 128 + kk];
            acc[r][0] = fmaf(a, w.x, acc[r][0]);
            acc[r][1] = fmaf(a, w.y, acc[r][1]);
            acc[r][2] = fmaf(a, w.z, acc[r][2]);
            acc[r][3] = fmaf(a, w.w, acc[r][3]);
        }
    }
    const float4 b4 = *(const float4*)(bl + c);
#pragma unroll
    for (int r = 0; r < 8; ++r) {
        const size_t base = (size_t)(row0 + r0 + r) * 128 + c;
        const float4 eb = *(const float4*)(emb + base);
        const float4 fu = *(const float4*)(f_up + base);
        float4 o;
        o.x = eb.x + fu.x * tanhf(acc[r][0] + b4.x);
        o.y = eb.y + fu.y * tanhf(acc[r][1] + b4.y);
        o.z = eb.z + fu.z * tanhf(acc[r][2] + b4.z);
        o.w = eb.w + fu.w * tanhf(acc[r][3] + b4.w);
        *(float4*)(df + base) = o;
    }
}

extern "C" void kernel_launch(void* const* d_in, const int* in_sizes, int n_in,
                              void* d_out, int out_size, void* d_ws, size_t ws_size,
                              hipStream_t stream) {
    const int* eidx = (const int*)d_in[0];
    const int* src = eidx;
    const int* dst = eidx + EE;
    const float* h_in  = (const float*)d_in[1];
    const float* mu_in = (const float*)d_in[2];
    const float* ev    = (const float*)d_in[3];
    const float* emb   = (const float*)d_in[4];
    const float* ewt   = (const float*)d_in[5];
    const float* nee   = (const float*)d_in[6];
    const float* W_q   = (const float*)d_in[7];  const float* b_q   = (const float*)d_in[8];
    const float* W_k   = (const float*)d_in[9];  const float* b_k   = (const float*)d_in[10];
    const float* W_gs1 = (const float*)d_in[11]; const float* b_gs1 = (const float*)d_in[12];
    const float* W_gs2 = (const float*)d_in[13]; const float* b_gs2 = (const float*)d_in[14];
    const float* W_gv1 = (const float*)d_in[15]; const float* b_gv1 = (const float*)d_in[16];
    const float* W_gv2 = (const float*)d_in[17]; const float* b_gv2 = (const float*)d_in[18];
    const float* W_phik= (const float*)d_in[19]; const float* b_phik= (const float*)d_in[20];
    const float* W_re  = (const float*)d_in[21]; const float* b_re  = (const float*)d_in[22];
    const float* W_vq  = (const float*)d_in[23];
    const float* W_vk0 = (const float*)d_in[24];
    const float* W_lin = (const float*)d_in[25]; const float* b_lin = (const float*)d_in[26];
    const float* W_eu1 = (const float*)d_in[27]; const float* b_eu1 = (const float*)d_in[28];
    const float* W_eu2 = (const float*)d_in[29]; const float* b_eu2 = (const float*)d_in[30];

    float* out    = (float*)d_out;
    float* h_out  = out;
    float* mu_out = out + (size_t)NN * ZZ;
    float* df     = out + (size_t)NN * ZZ * 4;

    const size_t NZ = (size_t)NN * ZZ, N3Z = (size_t)NN * 3 * ZZ, EZ = (size_t)EE * ZZ;
    const size_t EH = (size_t)EE * HH, NHs = (size_t)NN * HH;
    char* p = (char*)d_ws;
    float* qb    = (float*)p; p += NZ * 4;
    float* kb    = (float*)p; p += NZ * 4;
    float* tmpn  = (float*)p; p += NZ * 4;
    float* x3    = (float*)p; p += N3Z * 4;   // later reused for w1
    float* val3  = (float*)p; p += N3Z * 4;   // later reused for w2
    float* ebuf1 = (float*)p; p += EZ * 4;    // eu1-tmp -> r_attn -> w1d
    float* fup   = (float*)p; p += EZ * 4;
    float* ebuf3 = (float*)p; p += EZ * 4;    // w2d
    float* lg    = (float*)p; p += EH * 4;    // logits -> ex -> attn
    unsigned* mEnc = (unsigned*)p; p += NHs * 4;
    float* den   = (float*)p; p += NHs * 4;

    dim3 blk(256);
    // node-side GEMMs
    gemm_k128<0><<<dim3(NN / 64, 1), blk, 0, stream>>>(h_in, W_q, b_q, qb, 128);
    gemm_k128<0><<<dim3(NN / 64, 1), blk, 0, stream>>>(h_in, W_k, b_k, kb, 128);
    gemm_k128<1><<<dim3(NN / 64, 1), blk, 0, stream>>>(h_in, W_gs1, b_gs1, tmpn, 128);
    gemm_k128<0><<<dim3(NN / 64, 3), blk, 0, stream>>>(tmpn, W_gs2, b_gs2, x3, 384);
    gemm_k128<1><<<dim3(NN / 64, 1), blk, 0, stream>>>(h_in, W_gv1, b_gv1, tmpn, 128);
    gemm_k128<0><<<dim3(NN / 64, 3), blk, 0, stream>>>(tmpn, W_gv2, b_gv2, val3, 384);
    // edge-side: f_up = silu(emb@W_eu1+b)@W_eu2+b
    gemm_k128<1><<<dim3(EE / 64, 1), blk, 0, stream>>>(emb, W_eu1, b_eu1, ebuf1, 128);
    gemm_k128<0><<<dim3(EE / 64, 1), blk, 0, stream>>>(ebuf1, W_eu2, b_eu2, fup, 128);
    // r_attn = silu(emb@W_phik+b)
    gemm_k128<1><<<dim3(EE / 64, 1), blk, 0, stream>>>(emb, W_phik, b_phik, ebuf1, 128);
    // attention
    hipMemsetAsync(mEnc, 0, NHs * 4, stream);
    hipMemsetAsync(den, 0, NHs * 4, stream);
    logits_max_kernel<<<dim3(EH / 256), blk, 0, stream>>>(qb, kb, ebuf1, src, dst, lg, mEnc);
    exp_den_kernel<<<dim3(EH / 256), blk, 0, stream>>>(dst, mEnc, lg, den);
    attn_fin_kernel<<<dim3(EH / 256), blk, 0, stream>>>(dst, den, nee, lg);
    // init outputs then fused combine + scatter
    hipMemcpyAsync(h_out, h_in, NZ * 4, hipMemcpyDeviceToDevice, stream);
    hipMemcpyAsync(mu_out, mu_in, N3Z * 4, hipMemcpyDeviceToDevice, stream);
    combine_scatter_kernel<<<dim3(EE / 64), blk, 0, stream>>>(
        emb, W_re, b_re, lg, x3, val3, ewt, ev, mu_in, src, dst, h_out, mu_out);
    // vector branch: w1/w2 einsums (reuse x3/val3 buffers)
    gemm_k128<0><<<dim3(3 * NN / 64, 1), blk, 0, stream>>>(mu_out, W_vq, nullptr, x3, 128);
    gemm_k128<0><<<dim3(3 * NN / 64, 1), blk, 0, stream>>>(mu_out, W_vk0, nullptr, val3, 128);
    wd_kernel<<<dim3(EE * 32 / 256), blk, 0, stream>>>(x3, val3, ev, src, dst, ebuf1, ebuf3);
    wdot_df_kernel<<<dim3(EE / 64), blk, 0, stream>>>(ebuf1, ebuf3, W_lin, b_lin, emb, fup, df);
}

// Round 2
// 901.684 us; speedup vs baseline: 1.7374x; 1.7374x over previous
//
#include <hip/hip_runtime.h>
#include <math.h>

#define NN 16384
#define EE 131072
#define ZZ 128
#define HH 8

__device__ __forceinline__ float silu_f(float x) { return x / (1.0f + __expf(-x)); }

// order-preserving float->uint encoding for atomicMax
__device__ __forceinline__ unsigned fenc(float x) {
    unsigned b = __float_as_uint(x);
    return (b & 0x80000000u) ? ~b : (b | 0x80000000u);
}
__device__ __forceinline__ float fdec(unsigned e) {
    unsigned b = (e & 0x80000000u) ? (e & 0x7FFFFFFFu) : ~e;
    return __uint_as_float(b);
}

// C[M x P] = act(A[M x 128] @ W[128 x P] + bias), tile 64 rows x 128 cols.
template <int ACT>
__global__ __launch_bounds__(256) void gemm_k128(
    const float* __restrict__ A, const float* __restrict__ W,
    const float* __restrict__ bias, float* __restrict__ C, int P)
{
    __shared__ float As[64 * 128];
    const int row0 = blockIdx.x * 64;
    const int cg = blockIdx.y * 128;
    const int t = threadIdx.x;
    {
        const float4* Ag = (const float4*)(A + (size_t)row0 * 128);
        float4* As4 = (float4*)As;
#pragma unroll
        for (int i = 0; i < 8; ++i) As4[t + i * 256] = Ag[t + i * 256];
    }
    __syncthreads();
    const int c = (t & 31) * 4;
    const int r0 = (t >> 5) * 8;
    float acc[8][4];
#pragma unroll
    for (int r = 0; r < 8; ++r) { acc[r][0] = 0.f; acc[r][1] = 0.f; acc[r][2] = 0.f; acc[r][3] = 0.f; }
    const float* Wp = W + cg + c;
#pragma unroll 4
    for (int kk = 0; kk < 128; ++kk) {
        const float4 w = *(const float4*)(Wp + (size_t)kk * P);
#pragma unroll
        for (int r = 0; r < 8; ++r) {
            const float a = As[(r0 + r) * 128 + kk];
            acc[r][0] = fmaf(a, w.x, acc[r][0]);
            acc[r][1] = fmaf(a, w.y, acc[r][1]);
            acc[r][2] = fmaf(a, w.z, acc[r][2]);
            acc[r][3] = fmaf(a, w.w, acc[r][3]);
        }
    }
    float bx = 0.f, by = 0.f, bz = 0.f, bw = 0.f;
    if (bias) { const float4 b4 = *(const float4*)(bias + cg + c); bx = b4.x; by = b4.y; bz = b4.z; bw = b4.w; }
#pragma unroll
    for (int r = 0; r < 8; ++r) {
        float4 o;
        o.x = acc[r][0] + bx; o.y = acc[r][1] + by; o.z = acc[r][2] + bz; o.w = acc[r][3] + bw;
        if (ACT == 1) { o.x = silu_f(o.x); o.y = silu_f(o.y); o.z = silu_f(o.z); o.w = silu_f(o.w); }
        *(float4*)(C + (size_t)(row0 + r0 + r) * P + cg + c) = o;
    }
}

__global__ __launch_bounds__(256) void logits_max_kernel(
    const float* __restrict__ q, const float* __restrict__ k,
    const float* __restrict__ ra, const int* __restrict__ src,
    const int* __restrict__ dst, float* __restrict__ lg,
    unsigned* __restrict__ mEnc)
{
    const int idx = blockIdx.x * 256 + threadIdx.x;
    const int e = idx >> 3, h = idx & 7;
    const int s = src[e], d = dst[e];
    const float4* qp = (const float4*)(q + (size_t)d * 128 + h * 16);
    const float4* kp = (const float4*)(k + (size_t)s * 128 + h * 16);
    const float4* rp = (const float4*)(ra + (size_t)e * 128 + h * 16);
    float sum = 0.f;
#pragma unroll
    for (int i = 0; i < 4; ++i) {
        const float4 a = qp[i], b = kp[i], r = rp[i];
        sum += a.x * b.x * r.x + a.y * b.y * r.y + a.z * b.z * r.z + a.w * b.w * r.w;
    }
    lg[idx] = sum;
    atomicMax(&mEnc[d * 8 + h], fenc(sum));
}

__global__ __launch_bounds__(256) void exp_den_kernel(
    const int* __restrict__ dst, const unsigned* __restrict__ mEnc,
    float* __restrict__ lg, float* __restrict__ den)
{
    const int idx = blockIdx.x * 256 + threadIdx.x;
    const int e = idx >> 3, h = idx & 7;
    const int d = dst[e];
    const float m = fdec(mEnc[d * 8 + h]);
    const float ex = __expf(lg[idx] - m);
    lg[idx] = ex;
    atomicAdd(&den[d * 8 + h], ex);
}

__global__ __launch_bounds__(256) void attn_fin_kernel(
    const int* __restrict__ dst, const float* __restrict__ den,
    const float* __restrict__ nee, float* __restrict__ lg)
{
    const int idx = blockIdx.x * 256 + threadIdx.x;
    const int e = idx >> 3, h = idx & 7;
    const int d = dst[e];
    lg[idx] = lg[idx] / den[d * 8 + h] * sqrtf(nee[e]) * 0.08838834764831845f;
}

// ---- CSR build (dst-sorted) ----
__global__ __launch_bounds__(256) void hist_kernel(const int* __restrict__ dst, int* __restrict__ counts) {
    const int e = blockIdx.x * 256 + threadIdx.x;
    atomicAdd(&counts[dst[e]], 1);
}

// single block, 256 threads, N = 256*64
__global__ __launch_bounds__(256) void scan_kernel(const int* __restrict__ counts,
                                                   int* __restrict__ row_start,
                                                   int* __restrict__ cursor) {
    __shared__ int part[256];
    const int t = threadIdx.x;
    const int base = t * 64;
    int local[64];
    int s = 0;
#pragma unroll
    for (int i = 0; i < 64; ++i) { local[i] = s; s += counts[base + i]; }
    part[t] = s;
    __syncthreads();
    for (int off = 1; off < 256; off <<= 1) {
        int v = (t >= off) ? part[t - off] : 0;
        __syncthreads();
        part[t] += v;
        __syncthreads();
    }
    const int prev = (t == 0) ? 0 : part[t - 1];
#pragma unroll
    for (int i = 0; i < 64; ++i) {
        const int v = prev + local[i];
        row_start[base + i] = v;
        cursor[base + i] = v;
    }
    if (t == 255) row_start[NN] = prev + s;
}

__global__ __launch_bounds__(256) void fill_kernel(const int* __restrict__ dst,
                                                   int* __restrict__ cursor,
                                                   int* __restrict__ perm) {
    const int e = blockIdx.x * 256 + threadIdx.x;
    const int p = atomicAdd(&cursor[dst[e]], 1);
    perm[p] = e;
}

// Fused: r_ij = emb @ W_re + b_re, epilogue builds x_ij = cut*attn*val3[src]*x3[src]*r_ij
// and writes o_s/o_d/o_t COALESCED to workspace (no atomics).
__global__ __launch_bounds__(256) void combine_xij_kernel(
    const float* __restrict__ emb, const float* __restrict__ Wre,
    const float* __restrict__ bre, const float* __restrict__ attn,
    const float* __restrict__ x3, const float* __restrict__ val3,
    const float* __restrict__ ew, const int* __restrict__ src,
    float* __restrict__ osb, float* __restrict__ odb, float* __restrict__ otb)
{
    __shared__ float Es[64 * 128];
    const int e0 = blockIdx.x * 64;
    const int t = threadIdx.x;
    {
        const float4* Eg = (const float4*)(emb + (size_t)e0 * 128);
        float4* Es4 = (float4*)Es;
#pragma unroll
        for (int i = 0; i < 8; ++i) Es4[t + i * 256] = Eg[t + i * 256];
    }
    __syncthreads();
    const int c = (t & 31) * 4;
    const int r0 = (t >> 5) * 8;
    float acc0[8][4] = {}, acc1[8][4] = {}, acc2[8][4] = {};
    const float* W0 = Wre + c;
#pragma unroll 2
    for (int kk = 0; kk < 128; ++kk) {
        const float* Wr = W0 + kk * 384;
        const float4 w0 = *(const float4*)(Wr);
        const float4 w1 = *(const float4*)(Wr + 128);
        const float4 w2 = *(const float4*)(Wr + 256);
#pragma unroll
        for (int r = 0; r < 8; ++r) {
            const float a = Es[(r0 + r) * 128 + kk];
            acc0[r][0] = fmaf(a, w0.x, acc0[r][0]); acc0[r][1] = fmaf(a, w0.y, acc0[r][1]);
            acc0[r][2] = fmaf(a, w0.z, acc0[r][2]); acc0[r][3] = fmaf(a, w0.w, acc0[r][3]);
            acc1[r][0] = fmaf(a, w1.x, acc1[r][0]); acc1[r][1] = fmaf(a, w1.y, acc1[r][1]);
            acc1[r][2] = fmaf(a, w1.z, acc1[r][2]); acc1[r][3] = fmaf(a, w1.w, acc1[r][3]);
            acc2[r][0] = fmaf(a, w2.x, acc2[r][0]); acc2[r][1] = fmaf(a, w2.y, acc2[r][1]);
            acc2[r][2] = fmaf(a, w2.z, acc2[r][2]); acc2[r][3] = fmaf(a, w2.w, acc2[r][3]);
        }
    }
    const float4 b0 = *(const float4*)(bre + c);
    const float4 b1 = *(const float4*)(bre + 128 + c);
    const float4 b2 = *(const float4*)(bre + 256 + c);
    const int h0 = c / 48, h1 = (128 + c) / 48, h2 = (256 + c) / 48;
#pragma unroll
    for (int r = 0; r < 8; ++r) {
        const int e = e0 + r0 + r;
        const int s = src[e];
        const float w = ew[e];
        const float cut = (w < 5.0f) ? 0.5f * (cosf(w * 0.62831853071795864f) + 1.0f) : 0.0f;
        const float* ap = attn + (size_t)e * 8;
        const float a0 = ap[h0] * cut, a1 = ap[h1] * cut, a2 = ap[h2] * cut;
        const float* v3p = val3 + (size_t)s * 384;
        const float* x3p = x3 + (size_t)s * 384;
        const float4 v0 = *(const float4*)(v3p + c);
        const float4 xx0 = *(const float4*)(x3p + c);
        const float4 v1 = *(const float4*)(v3p + 128 + c);
        const float4 xx1 = *(const float4*)(x3p + 128 + c);
        const float4 v2 = *(const float4*)(v3p + 256 + c);
        const float4 xx2 = *(const float4*)(x3p + 256 + c);
        float4 os, od, ot;
        os.x = (acc0[r][0] + b0.x) * a0 * v0.x * xx0.x;
        os.y = (acc0[r][1] + b0.y) * a0 * v0.y * xx0.y;
        os.z = (acc0[r][2] + b0.z) * a0 * v0.z * xx0.z;
        os.w = (acc0[r][3] + b0.w) * a0 * v0.w * xx0.w;
        od.x = (acc1[r][0] + b1.x) * a1 * v1.x * xx1.x;
        od.y = (acc1[r][1] + b1.y) * a1 * v1.y * xx1.y;
        od.z = (acc1[r][2] + b1.z) * a1 * v1.z * xx1.z;
        od.w = (acc1[r][3] + b1.w) * a1 * v1.w * xx1.w;
        ot.x = (acc2[r][0] + b2.x) * a2 * v2.x * xx2.x;
        ot.y = (acc2[r][1] + b2.y) * a2 * v2.y * xx2.y;
        ot.z = (acc2[r][2] + b2.z) * a2 * v2.z * xx2.z;
        ot.w = (acc2[r][3] + b2.w) * a2 * v2.w * xx2.w;
        *(float4*)(osb + (size_t)e * 128 + c) = os;
        *(float4*)(odb + (size_t)e * 128 + c) = od;
        *(float4*)(otb + (size_t)e * 128 + c) = ot;
    }
}

// One 128-thread block per dst node: h_out = h_in + sum o_s;
// mu_out = mu_in + sum (o_d*ev_l + o_t*mu_in[src][l])
__global__ __launch_bounds__(128) void gather_kernel(
    const int* __restrict__ row_start, const int* __restrict__ perm,
    const int* __restrict__ src, const float* __restrict__ osb,
    const float* __restrict__ odb, const float* __restrict__ otb,
    const float* __restrict__ ev, const float* __restrict__ h_in,
    const float* __restrict__ mu_in, float* __restrict__ h_out,
    float* __restrict__ mu_out)
{
    const int n = blockIdx.x;
    const int t = threadIdx.x;  // z index 0..127
    const int beg = row_start[n], end = row_start[n + 1];
    float hacc = h_in[(size_t)n * 128 + t];
    float m0 = mu_in[(size_t)n * 384 + t];
    float m1 = mu_in[(size_t)n * 384 + 128 + t];
    float m2 = mu_in[(size_t)n * 384 + 256 + t];
    for (int i = beg; i < end; ++i) {
        const int e = perm[i];
        const int s = src[e];
        const float e0 = ev[e * 3 + 0], e1 = ev[e * 3 + 1], e2 = ev[e * 3 + 2];
        const float osv = osb[(size_t)e * 128 + t];
        const float odv = odb[(size_t)e * 128 + t];
        const float otv = otb[(size_t)e * 128 + t];
        const float* msp = mu_in + (size_t)s * 384 + t;
        hacc += osv;
        m0 += odv * e0 + otv * msp[0];
        m1 += odv * e1 + otv * msp[128];
        m2 += odv * e2 + otv * msp[256];
    }
    h_out[(size_t)n * 128 + t] = hacc;
    mu_out[(size_t)n * 384 + t] = m0;
    mu_out[(size_t)n * 384 + 128 + t] = m1;
    mu_out[(size_t)n * 384 + 256 + t] = m2;
}

__global__ __launch_bounds__(256) void wd_kernel(
    const float* __restrict__ w1, const float* __restrict__ w2,
    const float* __restrict__ ev, const int* __restrict__ src,
    const int* __restrict__ dst, float* __restrict__ w1d, float* __restrict__ w2d)
{
    const int idx = blockIdx.x * 256 + threadIdx.x;
    const int e = idx >> 5, zq = (idx & 31) * 4;
    const int s = src[e], d = dst[e];
    const float e0 = ev[e * 3 + 0], e1 = ev[e * 3 + 1], e2 = ev[e * 3 + 2];
    const float* p1 = w1 + (size_t)d * 384 + zq;
    const float* p2 = w2 + (size_t)s * 384 + zq;
    const float4 a0 = *(const float4*)(p1), a1 = *(const float4*)(p1 + 128), a2 = *(const float4*)(p1 + 256);
    const float4 c0 = *(const float4*)(p2), c1 = *(const float4*)(p2 + 128), c2 = *(const float4*)(p2 + 256);
    float4 o1, o2;
    o1.x = e0 * a0.x + e1 * a1.x + e2 * a2.x;
    o1.y = e0 * a0.y + e1 * a1.y + e2 * a2.y;
    o1.z = e0 * a0.z + e1 * a1.z + e2 * a2.z;
    o1.w = e0 * a0.w + e1 * a1.w + e2 * a2.w;
    o2.x = e0 * c0.x + e1 * c1.x + e2 * c2.x;
    o2.y = e0 * c0.y + e1 * c1.y + e2 * c2.y;
    o2.z = e0 * c0.z + e1 * c1.z + e2 * c2.z;
    o2.w = e0 * c0.w + e1 * c1.w + e2 * c2.w;
    *(float4*)(w1d + (size_t)e * 128 + zq) = o1;
    *(float4*)(w2d + (size_t)e * 128 + zq) = o2;
}

__global__ __launch_bounds__(256) void wdot_df_kernel(
    const float* __restrict__ w1d, const float* __restrict__ w2d,
    const float* __restrict__ Wl, const float* __restrict__ bl,
    const float* __restrict__ emb, const float* __restrict__ f_up,
    float* __restrict__ df)
{
    __shared__ float As[64 * 128];
    const int row0 = blockIdx.x * 64;
    const int t = threadIdx.x;
    {
        const float4* A1 = (const float4*)(w1d + (size_t)row0 * 128);
        const float4* A2 = (const float4*)(w2d + (size_t)row0 * 128);
        float4* As4 = (float4*)As;
#pragma unroll
        for (int i = 0; i < 8; ++i) {
            const float4 a = A1[t + i * 256];
            const float4 b = A2[t + i * 256];
            float4 p; p.x = a.x * b.x; p.y = a.y * b.y; p.z = a.z * b.z; p.w = a.w * b.w;
            As4[t + i * 256] = p;
        }
    }
    __syncthreads();
    const int c = (t & 31) * 4;
    const int r0 = (t >> 5) * 8;
    float acc[8][4];
#pragma unroll
    for (int r = 0; r < 8; ++r) { acc[r][0] = 0.f; acc[r][1] = 0.f; acc[r][2] = 0.f; acc[r][3] = 0.f; }
    const float* Wp = Wl + c;
#pragma unroll 4
    for (int kk = 0; kk < 128; ++kk) {
        const float4 w = *(const float4*)(Wp + (size_t)kk * 128);
#pragma unroll
        for (int r = 0; r < 8; ++r) {
            const float a = As[(r0 + r) * 128 + kk];
            acc[r][0] = fmaf(a, w.x, acc[r][0]);
            acc[r][1] = fmaf(a, w.y, acc[r][1]);
            acc[r][2] = fmaf(a, w.z, acc[r][2]);
            acc[r][3] = fmaf(a, w.w, acc[r][3]);
        }
    }
    const float4 b4 = *(const float4*)(bl + c);
#pragma unroll
    for (int r = 0; r < 8; ++r) {
        const size_t base = (size_t)(row0 + r0 + r) * 128 + c;
        const float4 eb = *(const float4*)(emb + base);
        const float4 fu = *(const float4*)(f_up + base);
        float4 o;
        o.x = eb.x + fu.x * tanhf(acc[r][0] + b4.x);
        o.y = eb.y + fu.y * tanhf(acc[r][1] + b4.y);
        o.z = eb.z + fu.z * tanhf(acc[r][2] + b4.z);
        o.w = eb.w + fu.w * tanhf(acc[r][3] + b4.w);
        *(float4*)(df + base) = o;
    }
}

extern "C" void kernel_launch(void* const* d_in, const int* in_sizes, int n_in,
                              void* d_out, int out_size, void* d_ws, size_t ws_size,
                              hipStream_t stream) {
    const int* eidx = (const int*)d_in[0];
    const int* src = eidx;
    const int* dst = eidx + EE;
    const float* h_in  = (const float*)d_in[1];
    const float* mu_in = (const float*)d_in[2];
    const float* ev    = (const float*)d_in[3];
    const float* emb   = (const float*)d_in[4];
    const float* ewt   = (const float*)d_in[5];
    const float* nee   = (const float*)d_in[6];
    const float* W_q   = (const float*)d_in[7];  const float* b_q   = (const float*)d_in[8];
    const float* W_k   = (const float*)d_in[9];  const float* b_k   = (const float*)d_in[10];
    const float* W_gs1 = (const float*)d_in[11]; const float* b_gs1 = (const float*)d_in[12];
    const float* W_gs2 = (const float*)d_in[13]; const float* b_gs2 = (const float*)d_in[14];
    const float* W_gv1 = (const float*)d_in[15]; const float* b_gv1 = (const float*)d_in[16];
    const float* W_gv2 = (const float*)d_in[17]; const float* b_gv2 = (const float*)d_in[18];
    const float* W_phik= (const float*)d_in[19]; const float* b_phik= (const float*)d_in[20];
    const float* W_re  = (const float*)d_in[21]; const float* b_re  = (const float*)d_in[22];
    const float* W_vq  = (const float*)d_in[23];
    const float* W_vk0 = (const float*)d_in[24];
    const float* W_lin = (const float*)d_in[25]; const float* b_lin = (const float*)d_in[26];
    const float* W_eu1 = (const float*)d_in[27]; const float* b_eu1 = (const float*)d_in[28];
    const float* W_eu2 = (const float*)d_in[29]; const float* b_eu2 = (const float*)d_in[30];

    float* out    = (float*)d_out;
    float* h_out  = out;
    float* mu_out = out + (size_t)NN * ZZ;
    float* df     = out + (size_t)NN * ZZ * 4;

    const size_t NZ = (size_t)NN * ZZ, N3Z = (size_t)NN * 3 * ZZ, EZ = (size_t)EE * ZZ;
    const size_t EH = (size_t)EE * HH, NHs = (size_t)NN * HH;
    char* p = (char*)d_ws;
    float* qb    = (float*)p; p += NZ * 4;
    float* kb    = (float*)p; p += NZ * 4;
    float* tmpn  = (float*)p; p += NZ * 4;
    float* x3    = (float*)p; p += N3Z * 4;   // later reused for w1
    float* val3  = (float*)p; p += N3Z * 4;   // later reused for w2
    float* ebuf1 = (float*)p; p += EZ * 4;    // eu1-tmp -> r_attn -> o_s -> w1d
    float* fup   = (float*)p; p += EZ * 4;
    float* ebuf3 = (float*)p; p += EZ * 4;    // o_d -> w2d
    float* otb   = (float*)p; p += EZ * 4;    // o_t
    float* lg    = (float*)p; p += EH * 4;    // logits -> ex -> attn
    unsigned* mEnc = (unsigned*)p; p += NHs * 4;
    float* den   = (float*)p; p += NHs * 4;
    int* counts  = (int*)p; p += NN * 4;
    int* cursor  = (int*)p; p += NN * 4;
    int* row_start = (int*)p; p += (NN + 1) * 4;
    int* perm    = (int*)p; p += EE * 4;

    dim3 blk(256);
    // node-side GEMMs
    gemm_k128<0><<<dim3(NN / 64, 1), blk, 0, stream>>>(h_in, W_q, b_q, qb, 128);
    gemm_k128<0><<<dim3(NN / 64, 1), blk, 0, stream>>>(h_in, W_k, b_k, kb, 128);
    gemm_k128<1><<<dim3(NN / 64, 1), blk, 0, stream>>>(h_in, W_gs1, b_gs1, tmpn, 128);
    gemm_k128<0><<<dim3(NN / 64, 3), blk, 0, stream>>>(tmpn, W_gs2, b_gs2, x3, 384);
    gemm_k128<1><<<dim3(NN / 64, 1), blk, 0, stream>>>(h_in, W_gv1, b_gv1, tmpn, 128);
    gemm_k128<0><<<dim3(NN / 64, 3), blk, 0, stream>>>(tmpn, W_gv2, b_gv2, val3, 384);
    // edge-side: f_up = silu(emb@W_eu1+b)@W_eu2+b
    gemm_k128<1><<<dim3(EE / 64, 1), blk, 0, stream>>>(emb, W_eu1, b_eu1, ebuf1, 128);
    gemm_k128<0><<<dim3(EE / 64, 1), blk, 0, stream>>>(ebuf1, W_eu2, b_eu2, fup, 128);
    // r_attn = silu(emb@W_phik+b)
    gemm_k128<1><<<dim3(EE / 64, 1), blk, 0, stream>>>(emb, W_phik, b_phik, ebuf1, 128);
    // CSR build (independent of GEMMs)
    hipMemsetAsync(counts, 0, NN * 4, stream);
    hipMemsetAsync(mEnc, 0, NHs * 4, stream);
    hipMemsetAsync(den, 0, NHs * 4, stream);
    hist_kernel<<<dim3(EE / 256), blk, 0, stream>>>(dst, counts);
    scan_kernel<<<dim3(1), blk, 0, stream>>>(counts, row_start, cursor);
    fill_kernel<<<dim3(EE / 256), blk, 0, stream>>>(dst, cursor, perm);
    // attention
    logits_max_kernel<<<dim3(EH / 256), blk, 0, stream>>>(qb, kb, ebuf1, src, dst, lg, mEnc);
    exp_den_kernel<<<dim3(EH / 256), blk, 0, stream>>>(dst, mEnc, lg, den);
    attn_fin_kernel<<<dim3(EH / 256), blk, 0, stream>>>(dst, den, nee, lg);
    // fused r_ij GEMM + x_ij epilogue, coalesced o_s/o_d/o_t writes
    combine_xij_kernel<<<dim3(EE / 64), blk, 0, stream>>>(
        emb, W_re, b_re, lg, x3, val3, ewt, src, ebuf1, ebuf3, otb);
    // atomic-free gather per dst node
    gather_kernel<<<dim3(NN), dim3(128), 0, stream>>>(
        row_start, perm, src, ebuf1, ebuf3, otb, ev, h_in, mu_in, h_out, mu_out);
    // vector branch: w1/w2 einsums (reuse x3/val3 buffers)
    gemm_k128<0><<<dim3(3 * NN / 64, 1), blk, 0, stream>>>(mu_out, W_vq, nullptr, x3, 128);
    gemm_k128<0><<<dim3(3 * NN / 64, 1), blk, 0, stream>>>(mu_out, W_vk0, nullptr, val3, 128);
    wd_kernel<<<dim3(EE * 32 / 256), blk, 0, stream>>>(x3, val3, ev, src, dst, ebuf1, ebuf3);
    wdot_df_kernel<<<dim3(EE / 64), blk, 0, stream>>>(ebuf1, ebuf3, W_lin, b_lin, emb, fup, df);
}

// Round 3
// 608.826 us; speedup vs baseline: 2.5731x; 1.4810x over previous
//
#include <hip/hip_runtime.h>
#include <math.h>

#define NN 16384
#define EE 131072
#define ZZ 128
#define HH 8

typedef short bf16x8 __attribute__((ext_vector_type(8)));
typedef float f32x4 __attribute__((ext_vector_type(4)));
typedef unsigned short ushort4v __attribute__((ext_vector_type(4)));
typedef unsigned short ushort8v __attribute__((ext_vector_type(8)));

__device__ __forceinline__ float silu_f(float x) { return x / (1.0f + __expf(-x)); }

__device__ __forceinline__ unsigned short f2bf(float x) {
    unsigned u = __float_as_uint(x);
    unsigned r = (u >> 16) & 1u;
    u += 0x7fffu + r;
    return (unsigned short)(u >> 16);
}

__device__ __forceinline__ f32x4 mfma16(bf16x8 a, bf16x8 b, f32x4 c) {
    return __builtin_amdgcn_mfma_f32_16x16x32_bf16(a, b, c, 0, 0, 0);
}

// order-preserving float->uint encoding for atomicMax
__device__ __forceinline__ unsigned fenc(float x) {
    unsigned b = __float_as_uint(x);
    return (b & 0x80000000u) ? ~b : (b | 0x80000000u);
}
__device__ __forceinline__ float fdec(unsigned e) {
    unsigned b = (e & 0x80000000u) ? (e & 0x7FFFFFFFu) : ~e;
    return __uint_as_float(b);
}

// ---- weight prep: W [128 x P] f32 -> Wt [P x 128] bf16 (transposed) ----
struct WPrep {
    const float* w[13];
    unsigned short* o[13];
    int P[13];
    int tile0[14];
};

__global__ __launch_bounds__(128) void prep_weights(WPrep wp) {
    int b = blockIdx.x, wi = 0;
    while (b >= wp.tile0[wi + 1]) ++wi;
    const int cg = (b - wp.tile0[wi]) * 128;
    const float* w = wp.w[wi];
    unsigned short* o = wp.o[wi];
    const int P = wp.P[wi];
    const int t = threadIdx.x;  // output row n = cg + t
    for (int k0 = 0; k0 < 128; k0 += 8) {
        ushort8v v;
#pragma unroll
        for (int j = 0; j < 8; ++j) v[j] = f2bf(w[(size_t)(k0 + j) * P + cg + t]);
        *(ushort8v*)(o + (size_t)(cg + t) * 128 + k0) = v;
    }
}

// ---- bf16 MFMA GEMM: C[M x P] = act(A[M x 128] @ Wt^T + bias) ----
// Wt is [P][128] bf16 pre-transposed. Tile 128x128, K=128 staged.
// ACT: 0 none, 1 silu, 2 multiply by aux[row*P+col]
template <int ACT>
__global__ __launch_bounds__(256, 2) void mm_bf16(
    const float* __restrict__ A, const unsigned short* __restrict__ Wt,
    const float* __restrict__ bias, float* __restrict__ C,
    const float* __restrict__ aux, int P)
{
    __shared__ uint4 lA4[2048];
    __shared__ uint4 lB4[2048];
    char* lA = (char*)lA4;
    char* lB = (char*)lB4;
    const int t = threadIdx.x;
    const size_t row0 = (size_t)blockIdx.x * 128;
    const int cg = blockIdx.y * 128;
    {
        const float4* Ag = (const float4*)(A + row0 * 128);
#pragma unroll
        for (int i = 0; i < 16; ++i) {
            const int f4 = t + i * 256;
            const int r = f4 >> 5, c4 = f4 & 31;
            const float4 v = Ag[f4];
            ushort4v bb;
            bb.x = f2bf(v.x); bb.y = f2bf(v.y); bb.z = f2bf(v.z); bb.w = f2bf(v.w);
            *(ushort4v*)(lA + ((r * 256 + c4 * 8) ^ ((r & 7) << 4))) = bb;
        }
    }
    {
        const uint4* Wg = (const uint4*)(Wt + (size_t)cg * 128);
#pragma unroll
        for (int i = 0; i < 8; ++i) {
            const int cid = t + i * 256;
            const int n = cid >> 4, c16 = cid & 15;
            *(uint4*)(lB + ((n * 256 + c16 * 16) ^ ((n & 7) << 4))) = Wg[cid];
        }
    }
    __syncthreads();
    const int lane = t & 63, wid = t >> 6;
    const int rbase = (wid >> 1) * 64, cbase = (wid & 1) * 64;
    const int lr = lane & 15, lgp = lane >> 4;
    f32x4 acc[4][4];
#pragma unroll
    for (int i = 0; i < 4; ++i)
#pragma unroll
        for (int j = 0; j < 4; ++j) acc[i][j] = (f32x4){0.f, 0.f, 0.f, 0.f};
#pragma unroll
    for (int ks = 0; ks < 4; ++ks) {
        bf16x8 av[4], bv[4];
#pragma unroll
        for (int mt = 0; mt < 4; ++mt) {
            const int r = rbase + mt * 16 + lr;
            av[mt] = *(const bf16x8*)(lA + ((r * 256 + ks * 64 + lgp * 16) ^ ((r & 7) << 4)));
        }
#pragma unroll
        for (int nt = 0; nt < 4; ++nt) {
            const int c = cbase + nt * 16 + lr;
            bv[nt] = *(const bf16x8*)(lB + ((c * 256 + ks * 64 + lgp * 16) ^ ((c & 7) << 4)));
        }
#pragma unroll
        for (int mt = 0; mt < 4; ++mt)
#pragma unroll
            for (int nt = 0; nt < 4; ++nt)
                acc[mt][nt] = mfma16(av[mt], bv[nt], acc[mt][nt]);
    }
#pragma unroll
    for (int nt = 0; nt < 4; ++nt) {
        const int col = cg + cbase + nt * 16 + lr;
        const float b = bias ? bias[col] : 0.f;
#pragma unroll
        for (int mt = 0; mt < 4; ++mt) {
#pragma unroll
            for (int j = 0; j < 4; ++j) {
                const size_t row = row0 + rbase + mt * 16 + lgp * 4 + j;
                float v = acc[mt][nt][j] + b;
                if (ACT == 1) v = silu_f(v);
                if (ACT == 2) v = v * aux[row * P + col];
                C[row * P + col] = v;
            }
        }
    }
}

// ---- fused r_ij MFMA GEMM + x_ij epilogue (coalesced writes) ----
__global__ __launch_bounds__(256, 2) void combine_mfma(
    const float* __restrict__ emb, const unsigned short* __restrict__ Wt_re,
    const float* __restrict__ bre, const float* __restrict__ attn,
    const float* __restrict__ xv, const float* __restrict__ ew,
    const int* __restrict__ src, float* __restrict__ osb,
    float* __restrict__ odb, float* __restrict__ otb)
{
    __shared__ uint4 lA4[2048];
    __shared__ uint4 lB4[2048];
    __shared__ float attnS[128 * 8];
    __shared__ float cutS[128];
    __shared__ int srcS[128];
    char* lA = (char*)lA4;
    char* lB = (char*)lB4;
    const int t = threadIdx.x;
    const size_t e0 = (size_t)blockIdx.x * 128;
    const int cg = blockIdx.y * 128;
    {
        const float4* Ag = (const float4*)(emb + e0 * 128);
#pragma unroll
        for (int i = 0; i < 16; ++i) {
            const int f4 = t + i * 256;
            const int r = f4 >> 5, c4 = f4 & 31;
            const float4 v = Ag[f4];
            ushort4v bb;
            bb.x = f2bf(v.x); bb.y = f2bf(v.y); bb.z = f2bf(v.z); bb.w = f2bf(v.w);
            *(ushort4v*)(lA + ((r * 256 + c4 * 8) ^ ((r & 7) << 4))) = bb;
        }
    }
    {
        const uint4* Wg = (const uint4*)(Wt_re + (size_t)cg * 128);
#pragma unroll
        for (int i = 0; i < 8; ++i) {
            const int cid = t + i * 256;
            const int n = cid >> 4, c16 = cid & 15;
            *(uint4*)(lB + ((n * 256 + c16 * 16) ^ ((n & 7) << 4))) = Wg[cid];
        }
    }
    if (t < 128) {
        const int e = e0 + t;
        const float w = ew[e];
        cutS[t] = (w < 5.0f) ? 0.5f * (cosf(w * 0.62831853071795864f) + 1.0f) : 0.0f;
        srcS[t] = src[e];
    }
    ((float4*)attnS)[t] = ((const float4*)(attn + e0 * 8))[t];
    __syncthreads();
    const int lane = t & 63, wid = t >> 6;
    const int rbase = (wid >> 1) * 64, cbase = (wid & 1) * 64;
    const int lr = lane & 15, lgp = lane >> 4;
    f32x4 acc[4][4];
#pragma unroll
    for (int i = 0; i < 4; ++i)
#pragma unroll
        for (int j = 0; j < 4; ++j) acc[i][j] = (f32x4){0.f, 0.f, 0.f, 0.f};
#pragma unroll
    for (int ks = 0; ks < 4; ++ks) {
        bf16x8 av[4], bv[4];
#pragma unroll
        for (int mt = 0; mt < 4; ++mt) {
            const int r = rbase + mt * 16 + lr;
            av[mt] = *(const bf16x8*)(lA + ((r * 256 + ks * 64 + lgp * 16) ^ ((r & 7) << 4)));
        }
#pragma unroll
        for (int nt = 0; nt < 4; ++nt) {
            const int c = cbase + nt * 16 + lr;
            bv[nt] = *(const bf16x8*)(lB + ((c * 256 + ks * 64 + lgp * 16) ^ ((c & 7) << 4)));
        }
#pragma unroll
        for (int mt = 0; mt < 4; ++mt)
#pragma unroll
            for (int nt = 0; nt < 4; ++nt)
                acc[mt][nt] = mfma16(av[mt], bv[nt], acc[mt][nt]);
    }
    float* buf = (cg == 0) ? osb : ((cg == 128) ? odb : otb);
#pragma unroll
    for (int nt = 0; nt < 4; ++nt) {
        const int col = cg + cbase + nt * 16 + lr;  // 0..383
        const int head = col / 48;
        const float b = bre[col];
        const int cc = col & 127;
#pragma unroll
        for (int mt = 0; mt < 4; ++mt) {
#pragma unroll
            for (int j = 0; j < 4; ++j) {
                const int er = rbase + mt * 16 + lgp * 4 + j;
                const size_t e = e0 + er;
                const int s = srcS[er];
                const float a = attnS[er * 8 + head] * cutS[er];
                const float o = (acc[mt][nt][j] + b) * a * xv[(size_t)s * 384 + col];
                buf[e * 128 + cc] = o;
            }
        }
    }
}

// ---- fused w_dot MFMA GEMM (A = w1d*w2d) + tanh/df epilogue ----
__global__ __launch_bounds__(256, 2) void wdot_mfma(
    const float* __restrict__ w1d, const float* __restrict__ w2d,
    const unsigned short* __restrict__ Wt_lin, const float* __restrict__ bl,
    const float* __restrict__ emb, const float* __restrict__ fup,
    float* __restrict__ df)
{
    __shared__ uint4 lA4[2048];
    __shared__ uint4 lB4[2048];
    char* lA = (char*)lA4;
    char* lB = (char*)lB4;
    const int t = threadIdx.x;
    const size_t e0 = (size_t)blockIdx.x * 128;
    {
        const float4* A1 = (const float4*)(w1d + e0 * 128);
        const float4* A2 = (const float4*)(w2d + e0 * 128);
#pragma unroll
        for (int i = 0; i < 16; ++i) {
            const int f4 = t + i * 256;
            const int r = f4 >> 5, c4 = f4 & 31;
            const float4 a = A1[f4];
            const float4 b = A2[f4];
            ushort4v bb;
            bb.x = f2bf(a.x * b.x); bb.y = f2bf(a.y * b.y);
            bb.z = f2bf(a.z * b.z); bb.w = f2bf(a.w * b.w);
            *(ushort4v*)(lA + ((r * 256 + c4 * 8) ^ ((r & 7) << 4))) = bb;
        }
    }
    {
        const uint4* Wg = (const uint4*)Wt_lin;
#pragma unroll
        for (int i = 0; i < 8; ++i) {
            const int cid = t + i * 256;
            const int n = cid >> 4, c16 = cid & 15;
            *(uint4*)(lB + ((n * 256 + c16 * 16) ^ ((n & 7) << 4))) = Wg[cid];
        }
    }
    __syncthreads();
    const int lane = t & 63, wid = t >> 6;
    const int rbase = (wid >> 1) * 64, cbase = (wid & 1) * 64;
    const int lr = lane & 15, lgp = lane >> 4;
    f32x4 acc[4][4];
#pragma unroll
    for (int i = 0; i < 4; ++i)
#pragma unroll
        for (int j = 0; j < 4; ++j) acc[i][j] = (f32x4){0.f, 0.f, 0.f, 0.f};
#pragma unroll
    for (int ks = 0; ks < 4; ++ks) {
        bf16x8 av[4], bv[4];
#pragma unroll
        for (int mt = 0; mt < 4; ++mt) {
            const int r = rbase + mt * 16 + lr;
            av[mt] = *(const bf16x8*)(lA + ((r * 256 + ks * 64 + lgp * 16) ^ ((r & 7) << 4)));
        }
#pragma unroll
        for (int nt = 0; nt < 4; ++nt) {
            const int c = cbase + nt * 16 + lr;
            bv[nt] = *(const bf16x8*)(lB + ((c * 256 + ks * 64 + lgp * 16) ^ ((c & 7) << 4)));
        }
#pragma unroll
        for (int mt = 0; mt < 4; ++mt)
#pragma unroll
            for (int nt = 0; nt < 4; ++nt)
                acc[mt][nt] = mfma16(av[mt], bv[nt], acc[mt][nt]);
    }
#pragma unroll
    for (int nt = 0; nt < 4; ++nt) {
        const int col = cbase + nt * 16 + lr;
        const float b = bl[col];
#pragma unroll
        for (int mt = 0; mt < 4; ++mt) {
#pragma unroll
            for (int j = 0; j < 4; ++j) {
                const size_t base = (e0 + rbase + mt * 16 + lgp * 4 + j) * 128 + col;
                const float v = tanhf(acc[mt][nt][j] + b);
                df[base] = emb[base] + fup[base] * v;
            }
        }
    }
}

// ---- attention ----
__global__ __launch_bounds__(256) void logits_max_kernel(
    const float* __restrict__ q, const float* __restrict__ k,
    const float* __restrict__ ra, const int* __restrict__ src,
    const int* __restrict__ dst, float* __restrict__ lg,
    unsigned* __restrict__ mEnc)
{
    const int idx = blockIdx.x * 256 + threadIdx.x;
    const int e = idx >> 3, h = idx & 7;
    const int s = src[e], d = dst[e];
    const float4* qp = (const float4*)(q + (size_t)d * 128 + h * 16);
    const float4* kp = (const float4*)(k + (size_t)s * 128 + h * 16);
    const float4* rp = (const float4*)(ra + (size_t)e * 128 + h * 16);
    float sum = 0.f;
#pragma unroll
    for (int i = 0; i < 4; ++i) {
        const float4 a = qp[i], b = kp[i], r = rp[i];
        sum += a.x * b.x * r.x + a.y * b.y * r.y + a.z * b.z * r.z + a.w * b.w * r.w;
    }
    lg[idx] = sum;
    atomicMax(&mEnc[d * 8 + h], fenc(sum));
}

__global__ __launch_bounds__(256) void exp_den_kernel(
    const int* __restrict__ dst, const unsigned* __restrict__ mEnc,
    float* __restrict__ lg, float* __restrict__ den)
{
    const int idx = blockIdx.x * 256 + threadIdx.x;
    const int e = idx >> 3, h = idx & 7;
    const int d = dst[e];
    const float m = fdec(mEnc[d * 8 + h]);
    const float ex = __expf(lg[idx] - m);
    lg[idx] = ex;
    atomicAdd(&den[d * 8 + h], ex);
}

__global__ __launch_bounds__(256) void attn_fin_kernel(
    const int* __restrict__ dst, const float* __restrict__ den,
    const float* __restrict__ nee, float* __restrict__ lg)
{
    const int idx = blockIdx.x * 256 + threadIdx.x;
    const int e = idx >> 3, h = idx & 7;
    const int d = dst[e];
    lg[idx] = lg[idx] / den[d * 8 + h] * sqrtf(nee[e]) * 0.08838834764831845f;
}

// ---- CSR build ----
__global__ __launch_bounds__(256) void hist_kernel(const int* __restrict__ dst, int* __restrict__ counts) {
    const int e = blockIdx.x * 256 + threadIdx.x;
    atomicAdd(&counts[dst[e]], 1);
}

__global__ __launch_bounds__(256) void scan_kernel(const int* __restrict__ counts,
                                                   int* __restrict__ row_start,
                                                   int* __restrict__ cursor) {
    __shared__ int part[256];
    const int t = threadIdx.x;
    const int base = t * 64;
    int local[64];
    int s = 0;
#pragma unroll
    for (int i = 0; i < 64; ++i) { local[i] = s; s += counts[base + i]; }
    part[t] = s;
    __syncthreads();
    for (int off = 1; off < 256; off <<= 1) {
        int v = (t >= off) ? part[t - off] : 0;
        __syncthreads();
        part[t] += v;
        __syncthreads();
    }
    const int prev = (t == 0) ? 0 : part[t - 1];
#pragma unroll
    for (int i = 0; i < 64; ++i) {
        const int v = prev + local[i];
        row_start[base + i] = v;
        cursor[base + i] = v;
    }
    if (t == 255) row_start[NN] = prev + s;
}

__global__ __launch_bounds__(256) void fill_kernel(const int* __restrict__ dst,
                                                   int* __restrict__ cursor,
                                                   int* __restrict__ perm) {
    const int e = blockIdx.x * 256 + threadIdx.x;
    const int p = atomicAdd(&cursor[dst[e]], 1);
    perm[p] = e;
}

// ---- gather per dst node ----
__global__ __launch_bounds__(128) void gather_kernel(
    const int* __restrict__ row_start, const int* __restrict__ perm,
    const int* __restrict__ src, const float* __restrict__ osb,
    const float* __restrict__ odb, const float* __restrict__ otb,
    const float* __restrict__ ev, const float* __restrict__ h_in,
    const float* __restrict__ mu_in, float* __restrict__ h_out,
    float* __restrict__ mu_out)
{
    const int n = blockIdx.x;
    const int t = threadIdx.x;
    const int beg = row_start[n], end = row_start[n + 1];
    float hacc = h_in[(size_t)n * 128 + t];
    float m0 = mu_in[(size_t)n * 384 + t];
    float m1 = mu_in[(size_t)n * 384 + 128 + t];
    float m2 = mu_in[(size_t)n * 384 + 256 + t];
    for (int i = beg; i < end; ++i) {
        const int e = perm[i];
        const int s = src[e];
        const float e0 = ev[e * 3 + 0], e1 = ev[e * 3 + 1], e2 = ev[e * 3 + 2];
        const float osv = osb[(size_t)e * 128 + t];
        const float odv = odb[(size_t)e * 128 + t];
        const float otv = otb[(size_t)e * 128 + t];
        const float* msp = mu_in + (size_t)s * 384 + t;
        hacc += osv;
        m0 += odv * e0 + otv * msp[0];
        m1 += odv * e1 + otv * msp[128];
        m2 += odv * e2 + otv * msp[256];
    }
    h_out[(size_t)n * 128 + t] = hacc;
    mu_out[(size_t)n * 384 + t] = m0;
    mu_out[(size_t)n * 384 + 128 + t] = m1;
    mu_out[(size_t)n * 384 + 256 + t] = m2;
}

__global__ __launch_bounds__(256) void wd_kernel(
    const float* __restrict__ w1, const float* __restrict__ w2,
    const float* __restrict__ ev, const int* __restrict__ src,
    const int* __restrict__ dst, float* __restrict__ w1d, float* __restrict__ w2d)
{
    const int idx = blockIdx.x * 256 + threadIdx.x;
    const int e = idx >> 5, zq = (idx & 31) * 4;
    const int s = src[e], d = dst[e];
    const float e0 = ev[e * 3 + 0], e1 = ev[e * 3 + 1], e2 = ev[e * 3 + 2];
    const float* p1 = w1 + (size_t)d * 384 + zq;
    const float* p2 = w2 + (size_t)s * 384 + zq;
    const float4 a0 = *(const float4*)(p1), a1 = *(const float4*)(p1 + 128), a2 = *(const float4*)(p1 + 256);
    const float4 c0 = *(const float4*)(p2), c1 = *(const float4*)(p2 + 128), c2 = *(const float4*)(p2 + 256);
    float4 o1, o2;
    o1.x = e0 * a0.x + e1 * a1.x + e2 * a2.x;
    o1.y = e0 * a0.y + e1 * a1.y + e2 * a2.y;
    o1.z = e0 * a0.z + e1 * a1.z + e2 * a2.z;
    o1.w = e0 * a0.w + e1 * a1.w + e2 * a2.w;
    o2.x = e0 * c0.x + e1 * c1.x + e2 * c2.x;
    o2.y = e0 * c0.y + e1 * c1.y + e2 * c2.y;
    o2.z = e0 * c0.z + e1 * c1.z + e2 * c2.z;
    o2.w = e0 * c0.w + e1 * c1.w + e2 * c2.w;
    *(float4*)(w1d + (size_t)e * 128 + zq) = o1;
    *(float4*)(w2d + (size_t)e * 128 + zq) = o2;
}

extern "C" void kernel_launch(void* const* d_in, const int* in_sizes, int n_in,
                              void* d_out, int out_size, void* d_ws, size_t ws_size,
                              hipStream_t stream) {
    const int* eidx = (const int*)d_in[0];
    const int* src = eidx;
    const int* dst = eidx + EE;
    const float* h_in  = (const float*)d_in[1];
    const float* mu_in = (const float*)d_in[2];
    const float* ev    = (const float*)d_in[3];
    const float* emb   = (const float*)d_in[4];
    const float* ewt   = (const float*)d_in[5];
    const float* nee   = (const float*)d_in[6];
    const float* W_q   = (const float*)d_in[7];  const float* b_q   = (const float*)d_in[8];
    const float* W_k   = (const float*)d_in[9];  const float* b_k   = (const float*)d_in[10];
    const float* W_gs1 = (const float*)d_in[11]; const float* b_gs1 = (const float*)d_in[12];
    const float* W_gs2 = (const float*)d_in[13]; const float* b_gs2 = (const float*)d_in[14];
    const float* W_gv1 = (const float*)d_in[15]; const float* b_gv1 = (const float*)d_in[16];
    const float* W_gv2 = (const float*)d_in[17]; const float* b_gv2 = (const float*)d_in[18];
    const float* W_phik= (const float*)d_in[19]; const float* b_phik= (const float*)d_in[20];
    const float* W_re  = (const float*)d_in[21]; const float* b_re  = (const float*)d_in[22];
    const float* W_vq  = (const float*)d_in[23];
    const float* W_vk0 = (const float*)d_in[24];
    const float* W_lin = (const float*)d_in[25]; const float* b_lin = (const float*)d_in[26];
    const float* W_eu1 = (const float*)d_in[27]; const float* b_eu1 = (const float*)d_in[28];
    const float* W_eu2 = (const float*)d_in[29]; const float* b_eu2 = (const float*)d_in[30];

    float* out    = (float*)d_out;
    float* h_out  = out;
    float* mu_out = out + (size_t)NN * ZZ;
    float* df     = out + (size_t)NN * ZZ * 4;

    const size_t NZ = (size_t)NN * ZZ, N3Z = (size_t)NN * 3 * ZZ, EZ = (size_t)EE * ZZ;
    const size_t EH = (size_t)EE * HH, NHs = (size_t)NN * HH;
    char* p = (char*)d_ws;
    float* qb    = (float*)p; p += NZ * 4;
    float* kb    = (float*)p; p += NZ * 4;
    float* tmpn  = (float*)p; p += NZ * 4;
    float* x3    = (float*)p; p += N3Z * 4;   // x3 -> (free) -> w1
    float* val3  = (float*)p; p += N3Z * 4;   // xv = x3*val3 -> w2
    float* ebuf1 = (float*)p; p += EZ * 4;    // eu1-tmp -> r_attn -> o_s -> w1d
    float* fup   = (float*)p; p += EZ * 4;
    float* ebuf3 = (float*)p; p += EZ * 4;    // o_d -> w2d
    float* otb   = (float*)p; p += EZ * 4;    // o_t
    float* lg    = (float*)p; p += EH * 4;    // logits -> ex -> attn
    unsigned short* wt = (unsigned short*)p; p += 2432 * 128 * 2;  // bf16 W^T pool
    unsigned* mEnc = (unsigned*)p; p += NHs * 4;
    float* den   = (float*)p; p += NHs * 4;
    int* counts  = (int*)p; p += NN * 4;
    int* cursor  = (int*)p; p += NN * 4;
    int* row_start = (int*)p; p += (NN + 1) * 4;
    int* perm    = (int*)p; p += EE * 4;

    // weight prep descriptors
    const float* wsrc[13] = {W_q, W_k, W_gs1, W_gs2, W_gv1, W_gv2, W_phik,
                             W_re, W_vq, W_vk0, W_lin, W_eu1, W_eu2};
    const int Ps[13] = {128, 128, 128, 384, 128, 384, 128, 384, 128, 128, 128, 128, 128};
    WPrep wp;
    unsigned short* wptr[13];
    int off = 0, tiles = 0;
    for (int i = 0; i < 13; ++i) {
        wp.w[i] = wsrc[i];
        wptr[i] = wt + (size_t)off * 128;
        wp.o[i] = wptr[i];
        wp.P[i] = Ps[i];
        wp.tile0[i] = tiles;
        off += Ps[i];
        tiles += Ps[i] / 128;
    }
    wp.tile0[13] = tiles;  // 19

    dim3 blk(256);
    prep_weights<<<dim3(tiles), dim3(128), 0, stream>>>(wp);
    // node-side GEMMs
    mm_bf16<0><<<dim3(NN / 128, 1), blk, 0, stream>>>(h_in, wptr[0], b_q, qb, nullptr, 128);
    mm_bf16<0><<<dim3(NN / 128, 1), blk, 0, stream>>>(h_in, wptr[1], b_k, kb, nullptr, 128);
    mm_bf16<1><<<dim3(NN / 128, 1), blk, 0, stream>>>(h_in, wptr[2], b_gs1, tmpn, nullptr, 128);
    mm_bf16<0><<<dim3(NN / 128, 3), blk, 0, stream>>>(tmpn, wptr[3], b_gs2, x3, nullptr, 384);
    mm_bf16<1><<<dim3(NN / 128, 1), blk, 0, stream>>>(h_in, wptr[4], b_gv1, tmpn, nullptr, 128);
    // gv2 with epilogue multiply by x3: val3 <- (tmpn@Wgv2+b) * x3  (= xv)
    mm_bf16<2><<<dim3(NN / 128, 3), blk, 0, stream>>>(tmpn, wptr[5], b_gv2, val3, x3, 384);
    // edge-side
    mm_bf16<1><<<dim3(EE / 128, 1), blk, 0, stream>>>(emb, wptr[11], b_eu1, ebuf1, nullptr, 128);
    mm_bf16<0><<<dim3(EE / 128, 1), blk, 0, stream>>>(ebuf1, wptr[12], b_eu2, fup, nullptr, 128);
    mm_bf16<1><<<dim3(EE / 128, 1), blk, 0, stream>>>(emb, wptr[6], b_phik, ebuf1, nullptr, 128);
    // CSR build
    hipMemsetAsync(counts, 0, NN * 4, stream);
    hipMemsetAsync(mEnc, 0, NHs * 4, stream);
    hipMemsetAsync(den, 0, NHs * 4, stream);
    hist_kernel<<<dim3(EE / 256), blk, 0, stream>>>(dst, counts);
    scan_kernel<<<dim3(1), blk, 0, stream>>>(counts, row_start, cursor);
    fill_kernel<<<dim3(EE / 256), blk, 0, stream>>>(dst, cursor, perm);
    // attention
    logits_max_kernel<<<dim3(EH / 256), blk, 0, stream>>>(qb, kb, ebuf1, src, dst, lg, mEnc);
    exp_den_kernel<<<dim3(EH / 256), blk, 0, stream>>>(dst, mEnc, lg, den);
    attn_fin_kernel<<<dim3(EH / 256), blk, 0, stream>>>(dst, den, nee, lg);
    // fused r_ij GEMM + x_ij epilogue
    combine_mfma<<<dim3(EE / 128, 3), blk, 0, stream>>>(
        emb, wptr[7], b_re, lg, val3, ewt, src, ebuf1, ebuf3, otb);
    // atomic-free gather
    gather_kernel<<<dim3(NN), dim3(128), 0, stream>>>(
        row_start, perm, src, ebuf1, ebuf3, otb, ev, h_in, mu_in, h_out, mu_out);
    // vector branch
    mm_bf16<0><<<dim3(3 * NN / 128, 1), blk, 0, stream>>>(mu_out, wptr[8], nullptr, x3, nullptr, 128);
    mm_bf16<0><<<dim3(3 * NN / 128, 1), blk, 0, stream>>>(mu_out, wptr[9], nullptr, val3, nullptr, 128);
    wd_kernel<<<dim3(EE * 32 / 256), blk, 0, stream>>>(x3, val3, ev, src, dst, ebuf1, ebuf3);
    wdot_mfma<<<dim3(EE / 128, 1), blk, 0, stream>>>(ebuf1, ebuf3, wptr[10], b_lin, emb, fup, df);
}

// Round 4
// 523.946 us; speedup vs baseline: 2.9899x; 1.1620x over previous
//
#include <hip/hip_runtime.h>
#include <math.h>

#define NN 16384
#define EE 131072
#define ZZ 128
#define HH 8

typedef short bf16x8 __attribute__((ext_vector_type(8)));
typedef float f32x4 __attribute__((ext_vector_type(4)));
typedef unsigned short ushort4v __attribute__((ext_vector_type(4)));
typedef unsigned short ushort8v __attribute__((ext_vector_type(8)));

__device__ __forceinline__ float silu_f(float x) { return x / (1.0f + __expf(-x)); }

__device__ __forceinline__ unsigned short f2bf(float x) {
    unsigned u = __float_as_uint(x);
    unsigned r = (u >> 16) & 1u;
    u += 0x7fffu + r;
    return (unsigned short)(u >> 16);
}
__device__ __forceinline__ float bf2f(unsigned short x) {
    return __uint_as_float(((unsigned)x) << 16);
}

__device__ __forceinline__ f32x4 mfma16(bf16x8 a, bf16x8 b, f32x4 c) {
    return __builtin_amdgcn_mfma_f32_16x16x32_bf16(a, b, c, 0, 0, 0);
}

__device__ __forceinline__ unsigned fenc(float x) {
    unsigned b = __float_as_uint(x);
    return (b & 0x80000000u) ? ~b : (b | 0x80000000u);
}
__device__ __forceinline__ float fdec(unsigned e) {
    unsigned b = (e & 0x80000000u) ? (e & 0x7FFFFFFFu) : ~e;
    return __uint_as_float(b);
}

// stage a [128 x 128] bf16 tile (rows = output cols) from pre-transposed Wt
__device__ __forceinline__ void stageB(const unsigned short* Wt, char* lB, int t) {
    const uint4* Wg = (const uint4*)Wt;
#pragma unroll
    for (int i = 0; i < 8; ++i) {
        const int cid = t + i * 256;
        const int n = cid >> 4, c16 = cid & 15;
        *(uint4*)(lB + ((n * 256 + c16 * 16) ^ ((n & 7) << 4))) = Wg[cid];
    }
}

// ---- weight prep: W [128 x P] f32 -> Wt [P x 128] bf16 (transposed) ----
struct WPrep {
    const float* w[13];
    unsigned short* o[13];
    int P[13];
    int tile0[14];
};

__global__ __launch_bounds__(128) void prep_weights(WPrep wp) {
    int b = blockIdx.x, wi = 0;
    while (b >= wp.tile0[wi + 1]) ++wi;
    const int cg = (b - wp.tile0[wi]) * 128;
    const float* w = wp.w[wi];
    unsigned short* o = wp.o[wi];
    const int P = wp.P[wi];
    const int t = threadIdx.x;
    for (int k0 = 0; k0 < 128; k0 += 8) {
        ushort8v v;
#pragma unroll
        for (int j = 0; j < 8; ++j) v[j] = f2bf(w[(size_t)(k0 + j) * P + cg + t]);
        *(ushort8v*)(o + (size_t)(cg + t) * 128 + k0) = v;
    }
}

// ---- bf16 MFMA GEMM: C[M x P] = act(A[M x 128] @ Wt^T + bias) ----
// ACT: 0 none, 1 silu, 2 multiply by aux[row*P+col] (f32)
// INBF: A dtype bf16(1)/f32(0); OUTBF: C dtype bf16(1)/f32(0)
template <int ACT, int INBF, int OUTBF>
__global__ __launch_bounds__(256, 2) void mm_bf16(
    const void* __restrict__ Av, const unsigned short* __restrict__ Wt,
    const float* __restrict__ bias, void* __restrict__ Cv,
    const float* __restrict__ aux, int P)
{
    __shared__ uint4 lA4[2048];
    __shared__ uint4 lB4[2048];
    char* lA = (char*)lA4;
    char* lB = (char*)lB4;
    const int t = threadIdx.x;
    const size_t row0 = (size_t)blockIdx.x * 128;
    const int cg = blockIdx.y * 128;
    if (INBF) {
        const uint4* Ag = (const uint4*)((const unsigned short*)Av + row0 * 128);
#pragma unroll
        for (int i = 0; i < 8; ++i) {
            const int chunk = t + i * 256;
            const int r = chunk >> 4, c16 = chunk & 15;
            *(uint4*)(lA + ((r * 256 + c16 * 16) ^ ((r & 7) << 4))) = Ag[chunk];
        }
    } else {
        const float4* Ag = (const float4*)((const float*)Av + row0 * 128);
#pragma unroll
        for (int i = 0; i < 16; ++i) {
            const int f4 = t + i * 256;
            const int r = f4 >> 5, c4 = f4 & 31;
            const float4 v = Ag[f4];
            ushort4v bb;
            bb.x = f2bf(v.x); bb.y = f2bf(v.y); bb.z = f2bf(v.z); bb.w = f2bf(v.w);
            *(ushort4v*)(lA + ((r * 256 + c4 * 8) ^ ((r & 7) << 4))) = bb;
        }
    }
    stageB(Wt + (size_t)cg * 128, lB, t);
    __syncthreads();
    const int lane = t & 63, wid = t >> 6;
    const int rbase = (wid >> 1) * 64, cbase = (wid & 1) * 64;
    const int lr = lane & 15, lgp = lane >> 4;
    f32x4 acc[4][4];
#pragma unroll
    for (int i = 0; i < 4; ++i)
#pragma unroll
        for (int j = 0; j < 4; ++j) acc[i][j] = (f32x4){0.f, 0.f, 0.f, 0.f};
#pragma unroll
    for (int ks = 0; ks < 4; ++ks) {
        bf16x8 av[4], bv[4];
#pragma unroll
        for (int mt = 0; mt < 4; ++mt) {
            const int r = rbase + mt * 16 + lr;
            av[mt] = *(const bf16x8*)(lA + ((r * 256 + ks * 64 + lgp * 16) ^ ((r & 7) << 4)));
        }
#pragma unroll
        for (int nt = 0; nt < 4; ++nt) {
            const int c = cbase + nt * 16 + lr;
            bv[nt] = *(const bf16x8*)(lB + ((c * 256 + ks * 64 + lgp * 16) ^ ((c & 7) << 4)));
        }
#pragma unroll
        for (int mt = 0; mt < 4; ++mt)
#pragma unroll
            for (int nt = 0; nt < 4; ++nt)
                acc[mt][nt] = mfma16(av[mt], bv[nt], acc[mt][nt]);
    }
#pragma unroll
    for (int nt = 0; nt < 4; ++nt) {
        const int col = cg + cbase + nt * 16 + lr;
        const float b = bias ? bias[col] : 0.f;
#pragma unroll
        for (int mt = 0; mt < 4; ++mt) {
#pragma unroll
            for (int j = 0; j < 4; ++j) {
                const size_t row = row0 + rbase + mt * 16 + lgp * 4 + j;
                float v = acc[mt][nt][j] + b;
                if (ACT == 1) v = silu_f(v);
                if (ACT == 2) v = v * aux[row * P + col];
                if (OUTBF) ((unsigned short*)Cv)[row * P + col] = f2bf(v);
                else ((float*)Cv)[row * P + col] = v;
            }
        }
    }
}

// ---- fused r_ij MFMA GEMM + x_ij epilogue; single emb stage, 3 col-groups ----
__global__ __launch_bounds__(256, 2) void combine_mfma(
    const float* __restrict__ emb, const unsigned short* __restrict__ Wt_re,
    const float* __restrict__ bre, const float* __restrict__ attn,
    const unsigned short* __restrict__ xv, const float* __restrict__ ew,
    const int* __restrict__ src, unsigned short* __restrict__ osb,
    unsigned short* __restrict__ odb, unsigned short* __restrict__ otb)
{
    __shared__ uint4 lA4[2048];
    __shared__ uint4 lB4[2048];
    __shared__ float attnS[128 * 8];
    __shared__ float cutS[128];
    __shared__ int srcS[128];
    char* lA = (char*)lA4;
    char* lB = (char*)lB4;
    const int t = threadIdx.x;
    const size_t e0 = (size_t)blockIdx.x * 128;
    {
        const float4* Ag = (const float4*)(emb + e0 * 128);
#pragma unroll
        for (int i = 0; i < 16; ++i) {
            const int f4 = t + i * 256;
            const int r = f4 >> 5, c4 = f4 & 31;
            const float4 v = Ag[f4];
            ushort4v bb;
            bb.x = f2bf(v.x); bb.y = f2bf(v.y); bb.z = f2bf(v.z); bb.w = f2bf(v.w);
            *(ushort4v*)(lA + ((r * 256 + c4 * 8) ^ ((r & 7) << 4))) = bb;
        }
    }
    stageB(Wt_re, lB, t);
    if (t < 128) {
        const int e = e0 + t;
        const float w = ew[e];
        cutS[t] = (w < 5.0f) ? 0.5f * (cosf(w * 0.62831853071795864f) + 1.0f) : 0.0f;
        srcS[t] = src[e];
    }
    ((float4*)attnS)[t] = ((const float4*)(attn + e0 * 8))[t];
    __syncthreads();
    const int lane = t & 63, wid = t >> 6;
    const int rbase = (wid >> 1) * 64, cbase = (wid & 1) * 64;
    const int lr = lane & 15, lgp = lane >> 4;
    // hoist A fragments (lA is never overwritten)
    bf16x8 avh[4][4];
#pragma unroll
    for (int ks = 0; ks < 4; ++ks)
#pragma unroll
        for (int mt = 0; mt < 4; ++mt) {
            const int r = rbase + mt * 16 + lr;
            avh[ks][mt] = *(const bf16x8*)(lA + ((r * 256 + ks * 64 + lgp * 16) ^ ((r & 7) << 4)));
        }
    unsigned short* bufs[3] = {osb, odb, otb};
    for (int cg3 = 0; cg3 < 3; ++cg3) {
        f32x4 acc[4][4];
#pragma unroll
        for (int i = 0; i < 4; ++i)
#pragma unroll
            for (int j = 0; j < 4; ++j) acc[i][j] = (f32x4){0.f, 0.f, 0.f, 0.f};
#pragma unroll
        for (int ks = 0; ks < 4; ++ks) {
            bf16x8 bv[4];
#pragma unroll
            for (int nt = 0; nt < 4; ++nt) {
                const int c = cbase + nt * 16 + lr;
                bv[nt] = *(const bf16x8*)(lB + ((c * 256 + ks * 64 + lgp * 16) ^ ((c & 7) << 4)));
            }
#pragma unroll
            for (int mt = 0; mt < 4; ++mt)
#pragma unroll
                for (int nt = 0; nt < 4; ++nt)
                    acc[mt][nt] = mfma16(avh[ks][mt], bv[nt], acc[mt][nt]);
        }
        unsigned short* buf = bufs[cg3];
        const int cgo = cg3 * 128;
#pragma unroll
        for (int nt = 0; nt < 4; ++nt) {
            const int col = cgo + cbase + nt * 16 + lr;  // 0..383
            const int head = col / 48;
            const float b = bre[col];
            const int cc = col & 127;
#pragma unroll
            for (int mt = 0; mt < 4; ++mt) {
#pragma unroll
                for (int j = 0; j < 4; ++j) {
                    const int er = rbase + mt * 16 + lgp * 4 + j;
                    const size_t e = e0 + er;
                    const int s = srcS[er];
                    const float a = attnS[er * 8 + head] * cutS[er];
                    const float o = (acc[mt][nt][j] + b) * a * bf2f(xv[(size_t)s * 384 + col]);
                    buf[e * 128 + cc] = f2bf(o);
                }
            }
        }
        if (cg3 < 2) {
            __syncthreads();
            stageB(Wt_re + (size_t)(cg3 + 1) * 128 * 128, lB, t);
            __syncthreads();
        }
    }
}

// ---- fused (wd + w_dot GEMM + tanh/df) ----
__global__ __launch_bounds__(256, 2) void wdot_fused(
    const unsigned short* __restrict__ w1, const unsigned short* __restrict__ w2,
    const float* __restrict__ ev, const int* __restrict__ src,
    const int* __restrict__ dst, const unsigned short* __restrict__ Wt_lin,
    const float* __restrict__ bl, const float* __restrict__ emb,
    const unsigned short* __restrict__ fup, float* __restrict__ df)
{
    __shared__ uint4 lA4[2048];
    __shared__ uint4 lB4[2048];
    char* lA = (char*)lA4;
    char* lB = (char*)lB4;
    const int t = threadIdx.x;
    const size_t e0 = (size_t)blockIdx.x * 128;
    stageB(Wt_lin, lB, t);
#pragma unroll
    for (int i = 0; i < 8; ++i) {
        const int chunk = t + i * 256;
        const int r = chunk >> 4, c8 = chunk & 15;
        const size_t e = e0 + r;
        const int s = src[e], d = dst[e];
        const float e0v = ev[e * 3 + 0], e1v = ev[e * 3 + 1], e2v = ev[e * 3 + 2];
        const ushort8v a0 = *(const ushort8v*)(w1 + (size_t)d * 384 + c8 * 8);
        const ushort8v a1 = *(const ushort8v*)(w1 + (size_t)d * 384 + 128 + c8 * 8);
        const ushort8v a2 = *(const ushort8v*)(w1 + (size_t)d * 384 + 256 + c8 * 8);
        const ushort8v c0 = *(const ushort8v*)(w2 + (size_t)s * 384 + c8 * 8);
        const ushort8v c1 = *(const ushort8v*)(w2 + (size_t)s * 384 + 128 + c8 * 8);
        const ushort8v c2 = *(const ushort8v*)(w2 + (size_t)s * 384 + 256 + c8 * 8);
        ushort8v o;
#pragma unroll
        for (int j = 0; j < 8; ++j) {
            const float av = e0v * bf2f(a0[j]) + e1v * bf2f(a1[j]) + e2v * bf2f(a2[j]);
            const float bv = e0v * bf2f(c0[j]) + e1v * bf2f(c1[j]) + e2v * bf2f(c2[j]);
            o[j] = f2bf(av * bv);
        }
        *(ushort8v*)(lA + ((r * 256 + c8 * 16) ^ ((r & 7) << 4))) = o;
    }
    __syncthreads();
    const int lane = t & 63, wid = t >> 6;
    const int rbase = (wid >> 1) * 64, cbase = (wid & 1) * 64;
    const int lr = lane & 15, lgp = lane >> 4;
    f32x4 acc[4][4];
#pragma unroll
    for (int i = 0; i < 4; ++i)
#pragma unroll
        for (int j = 0; j < 4; ++j) acc[i][j] = (f32x4){0.f, 0.f, 0.f, 0.f};
#pragma unroll
    for (int ks = 0; ks < 4; ++ks) {
        bf16x8 av[4], bv[4];
#pragma unroll
        for (int mt = 0; mt < 4; ++mt) {
            const int r = rbase + mt * 16 + lr;
            av[mt] = *(const bf16x8*)(lA + ((r * 256 + ks * 64 + lgp * 16) ^ ((r & 7) << 4)));
        }
#pragma unroll
        for (int nt = 0; nt < 4; ++nt) {
            const int c = cbase + nt * 16 + lr;
            bv[nt] = *(const bf16x8*)(lB + ((c * 256 + ks * 64 + lgp * 16) ^ ((c & 7) << 4)));
        }
#pragma unroll
        for (int mt = 0; mt < 4; ++mt)
#pragma unroll
            for (int nt = 0; nt < 4; ++nt)
                acc[mt][nt] = mfma16(av[mt], bv[nt], acc[mt][nt]);
    }
#pragma unroll
    for (int nt = 0; nt < 4; ++nt) {
        const int col = cbase + nt * 16 + lr;
        const float b = bl[col];
#pragma unroll
        for (int mt = 0; mt < 4; ++mt) {
#pragma unroll
            for (int j = 0; j < 4; ++j) {
                const size_t base = (e0 + rbase + mt * 16 + lgp * 4 + j) * 128 + col;
                const float v = tanhf(acc[mt][nt][j] + b);
                df[base] = emb[base] + bf2f(fup[base]) * v;
            }
        }
    }
}

// ---- attention ----
__global__ __launch_bounds__(256) void logits_max_kernel(
    const unsigned short* __restrict__ q, const unsigned short* __restrict__ k,
    const unsigned short* __restrict__ ra, const int* __restrict__ src,
    const int* __restrict__ dst, float* __restrict__ lg,
    unsigned* __restrict__ mEnc)
{
    const int idx = blockIdx.x * 256 + threadIdx.x;
    const int e = idx >> 3, h = idx & 7;
    const int s = src[e], d = dst[e];
    const ushort8v* qp = (const ushort8v*)(q + (size_t)d * 128 + h * 16);
    const ushort8v* kp = (const ushort8v*)(k + (size_t)s * 128 + h * 16);
    const ushort8v* rp = (const ushort8v*)(ra + (size_t)e * 128 + h * 16);
    float sum = 0.f;
#pragma unroll
    for (int i = 0; i < 2; ++i) {
        const ushort8v a = qp[i], b = kp[i], r = rp[i];
#pragma unroll
        for (int j = 0; j < 8; ++j) sum += bf2f(a[j]) * bf2f(b[j]) * bf2f(r[j]);
    }
    lg[idx] = sum;
    atomicMax(&mEnc[d * 8 + h], fenc(sum));
}

__global__ __launch_bounds__(256) void exp_den_kernel(
    const int* __restrict__ dst, const unsigned* __restrict__ mEnc,
    float* __restrict__ lg, float* __restrict__ den)
{
    const int idx = blockIdx.x * 256 + threadIdx.x;
    const int e = idx >> 3, h = idx & 7;
    const int d = dst[e];
    const float m = fdec(mEnc[d * 8 + h]);
    const float ex = __expf(lg[idx] - m);
    lg[idx] = ex;
    atomicAdd(&den[d * 8 + h], ex);
}

__global__ __launch_bounds__(256) void attn_fin_kernel(
    const int* __restrict__ dst, const float* __restrict__ den,
    const float* __restrict__ nee, float* __restrict__ lg)
{
    const int idx = blockIdx.x * 256 + threadIdx.x;
    const int e = idx >> 3, h = idx & 7;
    const int d = dst[e];
    lg[idx] = lg[idx] / den[d * 8 + h] * sqrtf(nee[e]) * 0.08838834764831845f;
}

// ---- CSR build ----
__global__ __launch_bounds__(256) void hist_kernel(const int* __restrict__ dst, int* __restrict__ counts) {
    const int e = blockIdx.x * 256 + threadIdx.x;
    atomicAdd(&counts[dst[e]], 1);
}

__global__ __launch_bounds__(256) void scan_kernel(const int* __restrict__ counts,
                                                   int* __restrict__ row_start,
                                                   int* __restrict__ cursor) {
    __shared__ int part[256];
    const int t = threadIdx.x;
    const int base = t * 64;
    int local[64];
    int s = 0;
#pragma unroll
    for (int i = 0; i < 64; ++i) { local[i] = s; s += counts[base + i]; }
    part[t] = s;
    __syncthreads();
    for (int off = 1; off < 256; off <<= 1) {
        int v = (t >= off) ? part[t - off] : 0;
        __syncthreads();
        part[t] += v;
        __syncthreads();
    }
    const int prev = (t == 0) ? 0 : part[t - 1];
#pragma unroll
    for (int i = 0; i < 64; ++i) {
        const int v = prev + local[i];
        row_start[base + i] = v;
        cursor[base + i] = v;
    }
    if (t == 255) row_start[NN] = prev + s;
}

__global__ __launch_bounds__(256) void fill_kernel(const int* __restrict__ dst,
                                                   int* __restrict__ cursor,
                                                   int* __restrict__ perm) {
    const int e = blockIdx.x * 256 + threadIdx.x;
    const int p = atomicAdd(&cursor[dst[e]], 1);
    perm[p] = e;
}

// ---- gather per dst node ----
__global__ __launch_bounds__(128) void gather_kernel(
    const int* __restrict__ row_start, const int* __restrict__ perm,
    const int* __restrict__ src, const unsigned short* __restrict__ osb,
    const unsigned short* __restrict__ odb, const unsigned short* __restrict__ otb,
    const float* __restrict__ ev, const float* __restrict__ h_in,
    const float* __restrict__ mu_in, float* __restrict__ h_out,
    float* __restrict__ mu_out)
{
    const int n = blockIdx.x;
    const int t = threadIdx.x;
    const int beg = row_start[n], end = row_start[n + 1];
    float hacc = h_in[(size_t)n * 128 + t];
    float m0 = mu_in[(size_t)n * 384 + t];
    float m1 = mu_in[(size_t)n * 384 + 128 + t];
    float m2 = mu_in[(size_t)n * 384 + 256 + t];
    for (int i = beg; i < end; ++i) {
        const int e = perm[i];
        const int s = src[e];
        const float e0 = ev[e * 3 + 0], e1 = ev[e * 3 + 1], e2 = ev[e * 3 + 2];
        const float osv = bf2f(osb[(size_t)e * 128 + t]);
        const float odv = bf2f(odb[(size_t)e * 128 + t]);
        const float otv = bf2f(otb[(size_t)e * 128 + t]);
        const float* msp = mu_in + (size_t)s * 384 + t;
        hacc += osv;
        m0 += odv * e0 + otv * msp[0];
        m1 += odv * e1 + otv * msp[128];
        m2 += odv * e2 + otv * msp[256];
    }
    h_out[(size_t)n * 128 + t] = hacc;
    mu_out[(size_t)n * 384 + t] = m0;
    mu_out[(size_t)n * 384 + 128 + t] = m1;
    mu_out[(size_t)n * 384 + 256 + t] = m2;
}

extern "C" void kernel_launch(void* const* d_in, const int* in_sizes, int n_in,
                              void* d_out, int out_size, void* d_ws, size_t ws_size,
                              hipStream_t stream) {
    const int* eidx = (const int*)d_in[0];
    const int* src = eidx;
    const int* dst = eidx + EE;
    const float* h_in  = (const float*)d_in[1];
    const float* mu_in = (const float*)d_in[2];
    const float* ev    = (const float*)d_in[3];
    const float* emb   = (const float*)d_in[4];
    const float* ewt   = (const float*)d_in[5];
    const float* nee   = (const float*)d_in[6];
    const float* W_q   = (const float*)d_in[7];  const float* b_q   = (const float*)d_in[8];
    const float* W_k   = (const float*)d_in[9];  const float* b_k   = (const float*)d_in[10];
    const float* W_gs1 = (const float*)d_in[11]; const float* b_gs1 = (const float*)d_in[12];
    const float* W_gs2 = (const float*)d_in[13]; const float* b_gs2 = (const float*)d_in[14];
    const float* W_gv1 = (const float*)d_in[15]; const float* b_gv1 = (const float*)d_in[16];
    const float* W_gv2 = (const float*)d_in[17]; const float* b_gv2 = (const float*)d_in[18];
    const float* W_phik= (const float*)d_in[19]; const float* b_phik= (const float*)d_in[20];
    const float* W_re  = (const float*)d_in[21]; const float* b_re  = (const float*)d_in[22];
    const float* W_vq  = (const float*)d_in[23];
    const float* W_vk0 = (const float*)d_in[24];
    const float* W_lin = (const float*)d_in[25]; const float* b_lin = (const float*)d_in[26];
    const float* W_eu1 = (const float*)d_in[27]; const float* b_eu1 = (const float*)d_in[28];
    const float* W_eu2 = (const float*)d_in[29]; const float* b_eu2 = (const float*)d_in[30];

    float* out    = (float*)d_out;
    float* h_out  = out;
    float* mu_out = out + (size_t)NN * ZZ;
    float* df     = out + (size_t)NN * ZZ * 4;

    const size_t NZ = (size_t)NN * ZZ, N3Z = (size_t)NN * 3 * ZZ, EZ = (size_t)EE * ZZ;
    const size_t EH = (size_t)EE * HH, NHs = (size_t)NN * HH;
    char* p = (char*)d_ws;
    unsigned short* qb   = (unsigned short*)p; p += NZ * 2;
    unsigned short* kb   = (unsigned short*)p; p += NZ * 2;
    unsigned short* tmpn = (unsigned short*)p; p += NZ * 2;   // gs1-out, then gv1-out
    float* x3            = (float*)p;          p += N3Z * 4;  // f32 aux for gv2
    unsigned short* xv   = (unsigned short*)p; p += N3Z * 2;  // x3*val3 bf16
    unsigned short* w1b  = (unsigned short*)p; p += N3Z * 2;
    unsigned short* w2b  = (unsigned short*)p; p += N3Z * 2;
    unsigned short* rab  = (unsigned short*)p; p += EZ * 2;   // r_attn
    unsigned short* tmpe = (unsigned short*)p; p += EZ * 2;   // eu1-out
    unsigned short* fup  = (unsigned short*)p; p += EZ * 2;
    unsigned short* osb  = (unsigned short*)p; p += EZ * 2;
    unsigned short* odb  = (unsigned short*)p; p += EZ * 2;
    unsigned short* otb  = (unsigned short*)p; p += EZ * 2;
    float* lg            = (float*)p;          p += EH * 4;
    unsigned short* wt   = (unsigned short*)p; p += 2432 * 128 * 2;
    unsigned* mEnc       = (unsigned*)p;       p += NHs * 4;
    float* den           = (float*)p;          p += NHs * 4;
    int* counts          = (int*)p;            p += NN * 4;
    int* cursor          = (int*)p;            p += NN * 4;
    int* row_start       = (int*)p;            p += (NN + 1) * 4;
    int* perm            = (int*)p;            p += EE * 4;

    const float* wsrc[13] = {W_q, W_k, W_gs1, W_gs2, W_gv1, W_gv2, W_phik,
                             W_re, W_vq, W_vk0, W_lin, W_eu1, W_eu2};
    const int Ps[13] = {128, 128, 128, 384, 128, 384, 128, 384, 128, 128, 128, 128, 128};
    WPrep wp;
    unsigned short* wptr[13];
    int off = 0, tiles = 0;
    for (int i = 0; i < 13; ++i) {
        wp.w[i] = wsrc[i];
        wptr[i] = wt + (size_t)off * 128;
        wp.o[i] = wptr[i];
        wp.P[i] = Ps[i];
        wp.tile0[i] = tiles;
        off += Ps[i];
        tiles += Ps[i] / 128;
    }
    wp.tile0[13] = tiles;

    dim3 blk(256);
    prep_weights<<<dim3(tiles), dim3(128), 0, stream>>>(wp);
    // node-side GEMMs
    mm_bf16<0,0,1><<<dim3(NN / 128, 1), blk, 0, stream>>>(h_in, wptr[0], b_q, qb, nullptr, 128);
    mm_bf16<0,0,1><<<dim3(NN / 128, 1), blk, 0, stream>>>(h_in, wptr[1], b_k, kb, nullptr, 128);
    mm_bf16<1,0,1><<<dim3(NN / 128, 1), blk, 0, stream>>>(h_in, wptr[2], b_gs1, tmpn, nullptr, 128);
    mm_bf16<0,1,0><<<dim3(NN / 128, 3), blk, 0, stream>>>(tmpn, wptr[3], b_gs2, x3, nullptr, 384);
    mm_bf16<1,0,1><<<dim3(NN / 128, 1), blk, 0, stream>>>(h_in, wptr[4], b_gv1, tmpn, nullptr, 128);
    mm_bf16<2,1,1><<<dim3(NN / 128, 3), blk, 0, stream>>>(tmpn, wptr[5], b_gv2, xv, x3, 384);
    // edge-side
    mm_bf16<1,0,1><<<dim3(EE / 128, 1), blk, 0, stream>>>(emb, wptr[11], b_eu1, tmpe, nullptr, 128);
    mm_bf16<0,1,1><<<dim3(EE / 128, 1), blk, 0, stream>>>(tmpe, wptr[12], b_eu2, fup, nullptr, 128);
    mm_bf16<1,0,1><<<dim3(EE / 128, 1), blk, 0, stream>>>(emb, wptr[6], b_phik, rab, nullptr, 128);
    // CSR build
    hipMemsetAsync(counts, 0, NN * 4, stream);
    hipMemsetAsync(mEnc, 0, NHs * 4, stream);
    hipMemsetAsync(den, 0, NHs * 4, stream);
    hist_kernel<<<dim3(EE / 256), blk, 0, stream>>>(dst, counts);
    scan_kernel<<<dim3(1), blk, 0, stream>>>(counts, row_start, cursor);
    fill_kernel<<<dim3(EE / 256), blk, 0, stream>>>(dst, cursor, perm);
    // attention
    logits_max_kernel<<<dim3(EH / 256), blk, 0, stream>>>(qb, kb, rab, src, dst, lg, mEnc);
    exp_den_kernel<<<dim3(EH / 256), blk, 0, stream>>>(dst, mEnc, lg, den);
    attn_fin_kernel<<<dim3(EH / 256), blk, 0, stream>>>(dst, den, nee, lg);
    // fused r_ij GEMM + x_ij epilogue (single emb stage, 3 col-groups)
    combine_mfma<<<dim3(EE / 128), blk, 0, stream>>>(
        emb, wptr[7], b_re, lg, xv, ewt, src, osb, odb, otb);
    // atomic-free gather
    gather_kernel<<<dim3(NN), dim3(128), 0, stream>>>(
        row_start, perm, src, osb, odb, otb, ev, h_in, mu_in, h_out, mu_out);
    // vector branch
    mm_bf16<0,0,1><<<dim3(3 * NN / 128, 1), blk, 0, stream>>>(mu_out, wptr[8], nullptr, w1b, nullptr, 128);
    mm_bf16<0,0,1><<<dim3(3 * NN / 128, 1), blk, 0, stream>>>(mu_out, wptr[9], nullptr, w2b, nullptr, 128);
    wdot_fused<<<dim3(EE / 128), blk, 0, stream>>>(
        w1b, w2b, ev, src, dst, wptr[10], b_lin, emb, fup, df);
}

// Round 5
// 460.368 us; speedup vs baseline: 3.4029x; 1.1381x over previous
//
#include <hip/hip_runtime.h>
#include <math.h>

#define NN 16384
#define EE 131072
#define ZZ 128
#define HH 8

typedef short bf16x8 __attribute__((ext_vector_type(8)));
typedef float f32x4 __attribute__((ext_vector_type(4)));
typedef unsigned short ushort4v __attribute__((ext_vector_type(4)));
typedef unsigned short ushort8v __attribute__((ext_vector_type(8)));

__device__ __forceinline__ float silu_f(float x) { return x / (1.0f + __expf(-x)); }

__device__ __forceinline__ unsigned short f2bf(float x) {
    unsigned u = __float_as_uint(x);
    unsigned r = (u >> 16) & 1u;
    u += 0x7fffu + r;
    return (unsigned short)(u >> 16);
}
__device__ __forceinline__ float bf2f(unsigned short x) {
    return __uint_as_float(((unsigned)x) << 16);
}

__device__ __forceinline__ f32x4 mfma16(bf16x8 a, bf16x8 b, f32x4 c) {
    return __builtin_amdgcn_mfma_f32_16x16x32_bf16(a, b, c, 0, 0, 0);
}

__device__ __forceinline__ unsigned fenc(float x) {
    unsigned b = __float_as_uint(x);
    return (b & 0x80000000u) ? ~b : (b | 0x80000000u);
}
__device__ __forceinline__ float fdec(unsigned e) {
    unsigned b = (e & 0x80000000u) ? (e & 0x7FFFFFFFu) : ~e;
    return __uint_as_float(b);
}

// stage a [128 x 128] bf16 tile (rows = output cols) from pre-transposed Wt
__device__ __forceinline__ void stageB(const unsigned short* Wt, char* lB, int t) {
    const uint4* Wg = (const uint4*)Wt;
#pragma unroll
    for (int i = 0; i < 8; ++i) {
        const int cid = t + i * 256;
        const int n = cid >> 4, c16 = cid & 15;
        *(uint4*)(lB + ((n * 256 + c16 * 16) ^ ((n & 7) << 4))) = Wg[cid];
    }
}

// ---- weight prep: W [128 x P] f32 -> Wt [P x 128] bf16 (transposed) ----
struct WPrep {
    const float* w[13];
    int P[13];
    int tile0[14];
};

__global__ __launch_bounds__(128) void prep_weights(WPrep wp, unsigned short* wt) {
    int b = blockIdx.x, wi = 0;
    while (b >= wp.tile0[wi + 1]) ++wi;
    const int cg = (b - wp.tile0[wi]) * 128;
    const float* w = wp.w[wi];
    unsigned short* o = wt + (size_t)wp.tile0[wi] * 16384;
    const int P = wp.P[wi];
    const int t = threadIdx.x;
    for (int k0 = 0; k0 < 128; k0 += 8) {
        ushort8v v;
#pragma unroll
        for (int j = 0; j < 8; ++j) v[j] = f2bf(w[(size_t)(k0 + j) * P + cg + t]);
        *(ushort8v*)(o + (size_t)(cg + t) * 128 + k0) = v;
    }
}

struct BPrep {
    const float* b[13];
    int off[14];
};

__global__ __launch_bounds__(256) void prep_bias(BPrep bp, float* bcat) {
    const int idx = blockIdx.x * 256 + threadIdx.x;
    if (idx >= 2432) return;
    int wi = 0;
    while (idx >= bp.off[wi + 1]) ++wi;
    bcat[idx] = bp.b[wi] ? bp.b[wi][idx - bp.off[wi]] : 0.f;
}

// ---- bf16 MFMA GEMM: C[M x P] = act(A[M x 128] @ Wt^T + bias), bf16 out ----
// ACT: 0 none, 1 silu, 2 multiply by bf16 aux[row*P+col]
// INBF: A dtype bf16(1)/f32(0). DUMP: also write staged bf16 A tile to dumpA.
// As = A row stride in elements. Output via LDS repack -> coalesced 16B stores.
template <int ACT, int INBF, int DUMP>
__global__ __launch_bounds__(256, 2) void mm_bf16(
    const void* __restrict__ Av, const unsigned short* __restrict__ Wt,
    const float* __restrict__ bias, unsigned short* __restrict__ C,
    const unsigned short* __restrict__ aux, unsigned short* __restrict__ dumpA,
    int P, int As)
{
    __shared__ uint4 lA4[2048];
    __shared__ uint4 lB4[2048];
    char* lA = (char*)lA4;
    char* lB = (char*)lB4;
    const int t = threadIdx.x;
    const size_t row0 = (size_t)blockIdx.x * 128;
    const int cg = blockIdx.y * 128;
    if (INBF) {
        const uint4* Ag = (const uint4*)((const unsigned short*)Av + row0 * As);
        const int rs = As >> 3;
#pragma unroll
        for (int i = 0; i < 8; ++i) {
            const int chunk = t + i * 256;
            const int r = chunk >> 4, c16 = chunk & 15;
            *(uint4*)(lA + ((r * 256 + c16 * 16) ^ ((r & 7) << 4))) = Ag[r * rs + c16];
        }
    } else {
        const float4* Ag = (const float4*)((const float*)Av + row0 * As);
        const int rs = As >> 2;
#pragma unroll
        for (int i = 0; i < 16; ++i) {
            const int f4 = t + i * 256;
            const int r = f4 >> 5, c4 = f4 & 31;
            const float4 v = Ag[r * rs + c4];
            ushort4v bb;
            bb.x = f2bf(v.x); bb.y = f2bf(v.y); bb.z = f2bf(v.z); bb.w = f2bf(v.w);
            *(ushort4v*)(lA + ((r * 256 + c4 * 8) ^ ((r & 7) << 4))) = bb;
        }
    }
    stageB(Wt + (size_t)cg * 128, lB, t);
    __syncthreads();
    if (DUMP) {
#pragma unroll
        for (int i = 0; i < 8; ++i) {
            const int ch = t + i * 256;
            const int row = ch >> 4, cpos = ch & 15;
            const uint4 v = *(const uint4*)(lA + ((row * 256 + cpos * 16) ^ ((row & 7) << 4)));
            *(uint4*)(dumpA + (row0 + row) * 128 + cpos * 8) = v;
        }
    }
    const int lane = t & 63, wid = t >> 6;
    const int rbase = (wid >> 1) * 64, cbase = (wid & 1) * 64;
    const int lr = lane & 15, lgp = lane >> 4;
    f32x4 acc[4][4];
#pragma unroll
    for (int i = 0; i < 4; ++i)
#pragma unroll
        for (int j = 0; j < 4; ++j) acc[i][j] = (f32x4){0.f, 0.f, 0.f, 0.f};
#pragma unroll
    for (int ks = 0; ks < 4; ++ks) {
        bf16x8 av[4], bv[4];
#pragma unroll
        for (int mt = 0; mt < 4; ++mt) {
            const int r = rbase + mt * 16 + lr;
            av[mt] = *(const bf16x8*)(lA + ((r * 256 + ks * 64 + lgp * 16) ^ ((r & 7) << 4)));
        }
#pragma unroll
        for (int nt = 0; nt < 4; ++nt) {
            const int c = cbase + nt * 16 + lr;
            bv[nt] = *(const bf16x8*)(lB + ((c * 256 + ks * 64 + lgp * 16) ^ ((c & 7) << 4)));
        }
#pragma unroll
        for (int mt = 0; mt < 4; ++mt)
#pragma unroll
            for (int nt = 0; nt < 4; ++nt)
                acc[mt][nt] = mfma16(av[mt], bv[nt], acc[mt][nt]);
    }
    // epilogue: repack through LDS (lB is free now) -> coalesced stores
    __syncthreads();
#pragma unroll
    for (int nt = 0; nt < 4; ++nt) {
        const int col = cbase + nt * 16 + lr;
        const int gcol = cg + col;
        const float b = bias[gcol];
#pragma unroll
        for (int mt = 0; mt < 4; ++mt) {
#pragma unroll
            for (int j = 0; j < 4; ++j) {
                const int row = rbase + mt * 16 + lgp * 4 + j;
                float v = acc[mt][nt][j] + b;
                if (ACT == 1) v = silu_f(v);
                if (ACT == 2) v = v * bf2f(aux[(row0 + row) * (size_t)P + gcol]);
                *(unsigned short*)(lB + ((row * 256 + col * 2) ^ ((row & 7) << 4))) = f2bf(v);
            }
        }
    }
    __syncthreads();
#pragma unroll
    for (int i = 0; i < 8; ++i) {
        const int ch = t + i * 256;
        const int row = ch >> 4, cpos = ch & 15;
        const uint4 v = *(const uint4*)(lB + ((row * 256 + cpos * 16) ^ ((row & 7) << 4)));
        *(uint4*)(C + (row0 + row) * (size_t)P + cg + cpos * 8) = v;
    }
}

// ---- fused r_ij MFMA GEMM + attn-finalize + x_ij epilogue ----
// o_s/o_d/o_t = (r_ij + b) * cut * attn_head  (xv factor applied in gather)
__global__ __launch_bounds__(256, 2) void combine_mfma(
    const unsigned short* __restrict__ embb, const unsigned short* __restrict__ Wt_re,
    const float* __restrict__ bre, const float* __restrict__ lg,
    const float* __restrict__ den, const float* __restrict__ nee,
    const int* __restrict__ dst, const float* __restrict__ ew,
    unsigned short* __restrict__ osb, unsigned short* __restrict__ odb,
    unsigned short* __restrict__ otb)
{
    __shared__ uint4 lA4[2048];
    __shared__ uint4 lB4[2048];
    __shared__ float attnS[128 * 8];
    __shared__ float cutS[128];
    char* lA = (char*)lA4;
    char* lB = (char*)lB4;
    const int t = threadIdx.x;
    const size_t e0 = (size_t)blockIdx.x * 128;
    {
        const uint4* Ag = (const uint4*)(embb + e0 * 128);
#pragma unroll
        for (int i = 0; i < 8; ++i) {
            const int chunk = t + i * 256;
            const int r = chunk >> 4, c16 = chunk & 15;
            *(uint4*)(lA + ((r * 256 + c16 * 16) ^ ((r & 7) << 4))) = Ag[chunk];
        }
    }
    stageB(Wt_re, lB, t);
    {
        const int er = t >> 1;
        const size_t e = e0 + er;
        const int h0 = (t & 1) * 4;
        const int d = dst[e];
        const float sc = sqrtf(nee[e]) * 0.08838834764831845f;
        const float4 ex4 = *(const float4*)(lg + e * 8 + h0);
        const float4 dn4 = *(const float4*)(den + (size_t)d * 8 + h0);
        float4 a4;
        a4.x = ex4.x / dn4.x * sc; a4.y = ex4.y / dn4.y * sc;
        a4.z = ex4.z / dn4.z * sc; a4.w = ex4.w / dn4.w * sc;
        *(float4*)(attnS + er * 8 + h0) = a4;
        if ((t & 1) == 0) {
            const float w = ew[e];
            cutS[er] = (w < 5.0f) ? 0.5f * (cosf(w * 0.62831853071795864f) + 1.0f) : 0.0f;
        }
    }
    __syncthreads();
    const int lane = t & 63, wid = t >> 6;
    const int rbase = (wid >> 1) * 64, cbase = (wid & 1) * 64;
    const int lr = lane & 15, lgp = lane >> 4;
    // hoist A fragments (lA reused as epilogue scratch afterwards)
    bf16x8 avh[4][4];
#pragma unroll
    for (int ks = 0; ks < 4; ++ks)
#pragma unroll
        for (int mt = 0; mt < 4; ++mt) {
            const int r = rbase + mt * 16 + lr;
            avh[ks][mt] = *(const bf16x8*)(lA + ((r * 256 + ks * 64 + lgp * 16) ^ ((r & 7) << 4)));
        }
    __syncthreads();
    unsigned short* bufs[3] = {osb, odb, otb};
    for (int cg3 = 0; cg3 < 3; ++cg3) {
        f32x4 acc[4][4];
#pragma unroll
        for (int i = 0; i < 4; ++i)
#pragma unroll
            for (int j = 0; j < 4; ++j) acc[i][j] = (f32x4){0.f, 0.f, 0.f, 0.f};
#pragma unroll
        for (int ks = 0; ks < 4; ++ks) {
            bf16x8 bv[4];
#pragma unroll
            for (int nt = 0; nt < 4; ++nt) {
                const int c = cbase + nt * 16 + lr;
                bv[nt] = *(const bf16x8*)(lB + ((c * 256 + ks * 64 + lgp * 16) ^ ((c & 7) << 4)));
            }
#pragma unroll
            for (int mt = 0; mt < 4; ++mt)
#pragma unroll
                for (int nt = 0; nt < 4; ++nt)
                    acc[mt][nt] = mfma16(avh[ks][mt], bv[nt], acc[mt][nt]);
        }
        const int cgo = cg3 * 128;
#pragma unroll
        for (int nt = 0; nt < 4; ++nt) {
            const int col = cbase + nt * 16 + lr;       // local 0..127
            const int gcol = cgo + col;                 // 0..383
            const int head = gcol / 48;
            const float b = bre[gcol];
#pragma unroll
            for (int mt = 0; mt < 4; ++mt) {
#pragma unroll
                for (int j = 0; j < 4; ++j) {
                    const int row = rbase + mt * 16 + lgp * 4 + j;
                    const float o = (acc[mt][nt][j] + b) * attnS[row * 8 + head] * cutS[row];
                    *(unsigned short*)(lA + ((row * 256 + col * 2) ^ ((row & 7) << 4))) = f2bf(o);
                }
            }
        }
        __syncthreads();
        unsigned short* buf = bufs[cg3];
#pragma unroll
        for (int i = 0; i < 8; ++i) {
            const int ch = t + i * 256;
            const int row = ch >> 4, cpos = ch & 15;
            const uint4 v = *(const uint4*)(lA + ((row * 256 + cpos * 16) ^ ((row & 7) << 4)));
            *(uint4*)(buf + (e0 + row) * 128 + cpos * 8) = v;
        }
        if (cg3 < 2) stageB(Wt_re + (size_t)(cg3 + 1) * 16384, lB, t);
        __syncthreads();
    }
}

// ---- fused (wd + w_dot GEMM + tanh/df) ----
__global__ __launch_bounds__(256, 2) void wdot_fused(
    const unsigned short* __restrict__ w12, const float* __restrict__ ev,
    const int* __restrict__ src, const int* __restrict__ dst,
    const unsigned short* __restrict__ Wt_lin, const float* __restrict__ bl,
    const unsigned short* __restrict__ embb, const unsigned short* __restrict__ fup,
    float* __restrict__ df)
{
    __shared__ uint4 lA4[2048];
    __shared__ uint4 lB4[2048];
    char* lA = (char*)lA4;
    char* lB = (char*)lB4;
    const int t = threadIdx.x;
    const size_t e0 = (size_t)blockIdx.x * 128;
    stageB(Wt_lin, lB, t);
#pragma unroll
    for (int i = 0; i < 8; ++i) {
        const int chunk = t + i * 256;
        const int r = chunk >> 4, c8 = chunk & 15;
        const size_t e = e0 + r;
        const int s = src[e], d = dst[e];
        const float e0v = ev[e * 3 + 0], e1v = ev[e * 3 + 1], e2v = ev[e * 3 + 2];
        const ushort8v a0 = *(const ushort8v*)(w12 + ((size_t)d * 3 + 0) * 256 + c8 * 8);
        const ushort8v a1 = *(const ushort8v*)(w12 + ((size_t)d * 3 + 1) * 256 + c8 * 8);
        const ushort8v a2 = *(const ushort8v*)(w12 + ((size_t)d * 3 + 2) * 256 + c8 * 8);
        const ushort8v c0 = *(const ushort8v*)(w12 + ((size_t)s * 3 + 0) * 256 + 128 + c8 * 8);
        const ushort8v c1 = *(const ushort8v*)(w12 + ((size_t)s * 3 + 1) * 256 + 128 + c8 * 8);
        const ushort8v c2 = *(const ushort8v*)(w12 + ((size_t)s * 3 + 2) * 256 + 128 + c8 * 8);
        ushort8v o;
#pragma unroll
        for (int j = 0; j < 8; ++j) {
            const float av = e0v * bf2f(a0[j]) + e1v * bf2f(a1[j]) + e2v * bf2f(a2[j]);
            const float bv = e0v * bf2f(c0[j]) + e1v * bf2f(c1[j]) + e2v * bf2f(c2[j]);
            o[j] = f2bf(av * bv);
        }
        *(ushort8v*)(lA + ((r * 256 + c8 * 16) ^ ((r & 7) << 4))) = o;
    }
    __syncthreads();
    const int lane = t & 63, wid = t >> 6;
    const int rbase = (wid >> 1) * 64, cbase = (wid & 1) * 64;
    const int lr = lane & 15, lgp = lane >> 4;
    f32x4 acc[4][4];
#pragma unroll
    for (int i = 0; i < 4; ++i)
#pragma unroll
        for (int j = 0; j < 4; ++j) acc[i][j] = (f32x4){0.f, 0.f, 0.f, 0.f};
#pragma unroll
    for (int ks = 0; ks < 4; ++ks) {
        bf16x8 av[4], bv[4];
#pragma unroll
        for (int mt = 0; mt < 4; ++mt) {
            const int r = rbase + mt * 16 + lr;
            av[mt] = *(const bf16x8*)(lA + ((r * 256 + ks * 64 + lgp * 16) ^ ((r & 7) << 4)));
        }
#pragma unroll
        for (int nt = 0; nt < 4; ++nt) {
            const int c = cbase + nt * 16 + lr;
            bv[nt] = *(const bf16x8*)(lB + ((c * 256 + ks * 64 + lgp * 16) ^ ((c & 7) << 4)));
        }
#pragma unroll
        for (int mt = 0; mt < 4; ++mt)
#pragma unroll
            for (int nt = 0; nt < 4; ++nt)
                acc[mt][nt] = mfma16(av[mt], bv[nt], acc[mt][nt]);
    }
#pragma unroll
    for (int nt = 0; nt < 4; ++nt) {
        const int col = cbase + nt * 16 + lr;
        const float b = bl[col];
#pragma unroll
        for (int mt = 0; mt < 4; ++mt) {
#pragma unroll
            for (int j = 0; j < 4; ++j) {
                const size_t base = (e0 + rbase + mt * 16 + lgp * 4 + j) * 128 + col;
                const float v = tanhf(acc[mt][nt][j] + b);
                df[base] = bf2f(embb[base]) + bf2f(fup[base]) * v;
            }
        }
    }
}

// ---- attention ----
__global__ __launch_bounds__(256) void logits_max_kernel(
    const unsigned short* __restrict__ qkb, const unsigned short* __restrict__ ra,
    const int* __restrict__ src, const int* __restrict__ dst,
    float* __restrict__ lg, unsigned* __restrict__ mEnc)
{
    const int idx = blockIdx.x * 256 + threadIdx.x;
    const int e = idx >> 3, h = idx & 7;
    const int s = src[e], d = dst[e];
    const ushort8v* qp = (const ushort8v*)(qkb + (size_t)d * 256 + h * 16);
    const ushort8v* kp = (const ushort8v*)(qkb + (size_t)s * 256 + 128 + h * 16);
    const ushort8v* rp = (const ushort8v*)(ra + (size_t)e * 128 + h * 16);
    float sum = 0.f;
#pragma unroll
    for (int i = 0; i < 2; ++i) {
        const ushort8v a = qp[i], b = kp[i], r = rp[i];
#pragma unroll
        for (int j = 0; j < 8; ++j) sum += bf2f(a[j]) * bf2f(b[j]) * bf2f(r[j]);
    }
    lg[idx] = sum;
    atomicMax(&mEnc[d * 8 + h], fenc(sum));
}

__global__ __launch_bounds__(256) void exp_den_kernel(
    const int* __restrict__ dst, const unsigned* __restrict__ mEnc,
    float* __restrict__ lg, float* __restrict__ den)
{
    const int idx = blockIdx.x * 256 + threadIdx.x;
    const int e = idx >> 3, h = idx & 7;
    const int d = dst[e];
    const float m = fdec(mEnc[d * 8 + h]);
    const float ex = __expf(lg[idx] - m);
    lg[idx] = ex;
    atomicAdd(&den[d * 8 + h], ex);
}

// ---- CSR build ----
__global__ __launch_bounds__(256) void hist_kernel(const int* __restrict__ dst, int* __restrict__ counts) {
    const int e = blockIdx.x * 256 + threadIdx.x;
    atomicAdd(&counts[dst[e]], 1);
}

__global__ __launch_bounds__(256) void scan_kernel(const int* __restrict__ counts,
                                                   int* __restrict__ row_start,
                                                   int* __restrict__ cursor) {
    __shared__ int part[256];
    const int t = threadIdx.x;
    const int base = t * 64;
    int local[64];
    int s = 0;
#pragma unroll
    for (int i = 0; i < 64; ++i) { local[i] = s; s += counts[base + i]; }
    part[t] = s;
    __syncthreads();
    for (int off = 1; off < 256; off <<= 1) {
        int v = (t >= off) ? part[t - off] : 0;
        __syncthreads();
        part[t] += v;
        __syncthreads();
    }
    const int prev = (t == 0) ? 0 : part[t - 1];
#pragma unroll
    for (int i = 0; i < 64; ++i) {
        const int v = prev + local[i];
        row_start[base + i] = v;
        cursor[base + i] = v;
    }
    if (t == 255) row_start[NN] = prev + s;
}

__global__ __launch_bounds__(256) void fill_kernel(const int* __restrict__ dst,
                                                   int* __restrict__ cursor,
                                                   int* __restrict__ perm) {
    const int e = blockIdx.x * 256 + threadIdx.x;
    const int p = atomicAdd(&cursor[dst[e]], 1);
    perm[p] = e;
}

// ---- gather per dst node (applies xv = x3*val3 factor here) ----
__global__ __launch_bounds__(128) void gather_kernel(
    const int* __restrict__ row_start, const int* __restrict__ perm,
    const int* __restrict__ src, const unsigned short* __restrict__ osb,
    const unsigned short* __restrict__ odb, const unsigned short* __restrict__ otb,
    const unsigned short* __restrict__ xv, const float* __restrict__ ev,
    const float* __restrict__ h_in, const float* __restrict__ mu_in,
    float* __restrict__ h_out, float* __restrict__ mu_out)
{
    const int n = blockIdx.x;
    const int t = threadIdx.x;
    const int beg = row_start[n], end = row_start[n + 1];
    float hacc = h_in[(size_t)n * 128 + t];
    float m0 = mu_in[(size_t)n * 384 + t];
    float m1 = mu_in[(size_t)n * 384 + 128 + t];
    float m2 = mu_in[(size_t)n * 384 + 256 + t];
    for (int i = beg; i < end; ++i) {
        const int e = perm[i];
        const int s = src[e];
        const float e0 = ev[e * 3 + 0], e1 = ev[e * 3 + 1], e2 = ev[e * 3 + 2];
        const unsigned short* xp = xv + (size_t)s * 384 + t;
        const float osv = bf2f(osb[(size_t)e * 128 + t]) * bf2f(xp[0]);
        const float odv = bf2f(odb[(size_t)e * 128 + t]) * bf2f(xp[128]);
        const float otv = bf2f(otb[(size_t)e * 128 + t]) * bf2f(xp[256]);
        const float* msp = mu_in + (size_t)s * 384 + t;
        hacc += osv;
        m0 += odv * e0 + otv * msp[0];
        m1 += odv * e1 + otv * msp[128];
        m2 += odv * e2 + otv * msp[256];
    }
    h_out[(size_t)n * 128 + t] = hacc;
    mu_out[(size_t)n * 384 + t] = m0;
    mu_out[(size_t)n * 384 + 128 + t] = m1;
    mu_out[(size_t)n * 384 + 256 + t] = m2;
}

extern "C" void kernel_launch(void* const* d_in, const int* in_sizes, int n_in,
                              void* d_out, int out_size, void* d_ws, size_t ws_size,
                              hipStream_t stream) {
    const int* eidx = (const int*)d_in[0];
    const int* src = eidx;
    const int* dst = eidx + EE;
    const float* h_in  = (const float*)d_in[1];
    const float* mu_in = (const float*)d_in[2];
    const float* ev    = (const float*)d_in[3];
    const float* emb   = (const float*)d_in[4];
    const float* ewt   = (const float*)d_in[5];
    const float* nee   = (const float*)d_in[6];
    const float* W_q   = (const float*)d_in[7];  const float* b_q   = (const float*)d_in[8];
    const float* W_k   = (const float*)d_in[9];  const float* b_k   = (const float*)d_in[10];
    const float* W_gs1 = (const float*)d_in[11]; const float* b_gs1 = (const float*)d_in[12];
    const float* W_gs2 = (const float*)d_in[13]; const float* b_gs2 = (const float*)d_in[14];
    const float* W_gv1 = (const float*)d_in[15]; const float* b_gv1 = (const float*)d_in[16];
    const float* W_gv2 = (const float*)d_in[17]; const float* b_gv2 = (const float*)d_in[18];
    const float* W_phik= (const float*)d_in[19]; const float* b_phik= (const float*)d_in[20];
    const float* W_re  = (const float*)d_in[21]; const float* b_re  = (const float*)d_in[22];
    const float* W_vq  = (const float*)d_in[23];
    const float* W_vk0 = (const float*)d_in[24];
    const float* W_lin = (const float*)d_in[25]; const float* b_lin = (const float*)d_in[26];
    const float* W_eu1 = (const float*)d_in[27]; const float* b_eu1 = (const float*)d_in[28];
    const float* W_eu2 = (const float*)d_in[29]; const float* b_eu2 = (const float*)d_in[30];

    float* out    = (float*)d_out;
    float* h_out  = out;
    float* mu_out = out + (size_t)NN * ZZ;
    float* df     = out + (size_t)NN * ZZ * 4;

    const size_t NZ = (size_t)NN * ZZ, N3Z = (size_t)NN * 3 * ZZ, EZ = (size_t)EE * ZZ;
    const size_t EH = (size_t)EE * HH, NHs = (size_t)NN * HH;
    char* p = (char*)d_ws;
    unsigned short* qkb   = (unsigned short*)p; p += NZ * 2 * 2;   // N x 256 (q|k)
    unsigned short* tmpn2 = (unsigned short*)p; p += NZ * 2 * 2;   // N x 256 (gs1|gv1)
    unsigned short* x3b   = (unsigned short*)p; p += N3Z * 2;      // N x 384
    unsigned short* xv    = (unsigned short*)p; p += N3Z * 2;      // N x 384
    unsigned short* w12   = (unsigned short*)p; p += N3Z * 2 * 2;  // 3N x 256 (w1|w2)
    unsigned short* embb  = (unsigned short*)p; p += EZ * 2;
    unsigned short* rab   = (unsigned short*)p; p += EZ * 2;
    unsigned short* tmpe  = (unsigned short*)p; p += EZ * 2;
    unsigned short* fup   = (unsigned short*)p; p += EZ * 2;
    unsigned short* osb   = (unsigned short*)p; p += EZ * 2;
    unsigned short* odb   = (unsigned short*)p; p += EZ * 2;
    unsigned short* otb   = (unsigned short*)p; p += EZ * 2;
    float* lg             = (float*)p;          p += EH * 4;
    unsigned short* wt    = (unsigned short*)p; p += 2432 * 128 * 2;
    float* bcat           = (float*)p;          p += 2432 * 4;
    unsigned* mEnc        = (unsigned*)p;       p += NHs * 4;
    float* den            = (float*)p;          p += NHs * 4;
    int* counts           = (int*)p;            p += NN * 4;
    int* cursor           = (int*)p;            p += NN * 4;
    int* row_start        = (int*)p;            p += (NN + 1) * 4;
    int* perm             = (int*)p;            p += EE * 4;

    // pool order: q,k,gs1,gv1,gs2,gv2,phik,re,vq,vk0,lin,eu1,eu2
    const float* wsrc[13] = {W_q, W_k, W_gs1, W_gv1, W_gs2, W_gv2, W_phik,
                             W_re, W_vq, W_vk0, W_lin, W_eu1, W_eu2};
    const float* bsrc[13] = {b_q, b_k, b_gs1, b_gv1, b_gs2, b_gv2, b_phik,
                             b_re, nullptr, nullptr, b_lin, b_eu1, b_eu2};
    const int Ps[13] = {128, 128, 128, 128, 384, 384, 128, 384, 128, 128, 128, 128, 128};
    WPrep wp; BPrep bp;
    int tiles = 0;
    for (int i = 0; i < 13; ++i) {
        wp.w[i] = wsrc[i]; wp.P[i] = Ps[i]; wp.tile0[i] = tiles;
        bp.b[i] = bsrc[i]; bp.off[i] = tiles * 128;
        tiles += Ps[i] / 128;
    }
    wp.tile0[13] = tiles; bp.off[13] = tiles * 128;  // 19 tiles, 2432 cols
    unsigned short* wT[13]; const float* bC[13];
    for (int i = 0; i < 13; ++i) { wT[i] = wt + (size_t)wp.tile0[i] * 16384; bC[i] = bcat + bp.off[i]; }

    dim3 blk(256);
    prep_weights<<<dim3(tiles), dim3(128), 0, stream>>>(wp, wt);
    prep_bias<<<dim3(10), blk, 0, stream>>>(bp, bcat);
    // node-side GEMMs (merged)
    mm_bf16<0,0,0><<<dim3(NN/128, 2), blk, 0, stream>>>(h_in, wT[0], bC[0], qkb, nullptr, nullptr, 256, 128);
    mm_bf16<1,0,0><<<dim3(NN/128, 2), blk, 0, stream>>>(h_in, wT[2], bC[2], tmpn2, nullptr, nullptr, 256, 128);
    mm_bf16<0,1,0><<<dim3(NN/128, 3), blk, 0, stream>>>(tmpn2, wT[4], bC[4], x3b, nullptr, nullptr, 384, 256);
    mm_bf16<2,1,0><<<dim3(NN/128, 3), blk, 0, stream>>>(tmpn2 + 128, wT[5], bC[5], xv, x3b, nullptr, 384, 256);
    // edge-side: eu1 (dumps bf16 emb), eu2, phik (bf16 emb input)
    mm_bf16<1,0,1><<<dim3(EE/128, 1), blk, 0, stream>>>(emb, wT[11], bC[11], tmpe, nullptr, embb, 128, 128);
    mm_bf16<0,1,0><<<dim3(EE/128, 1), blk, 0, stream>>>(tmpe, wT[12], bC[12], fup, nullptr, nullptr, 128, 128);
    mm_bf16<1,1,0><<<dim3(EE/128, 1), blk, 0, stream>>>(embb, wT[6], bC[6], rab, nullptr, nullptr, 128, 128);
    // CSR build
    hipMemsetAsync(counts, 0, NN * 4, stream);
    hipMemsetAsync(mEnc, 0, NHs * 4, stream);
    hipMemsetAsync(den, 0, NHs * 4, stream);
    hist_kernel<<<dim3(EE/256), blk, 0, stream>>>(dst, counts);
    scan_kernel<<<dim3(1), blk, 0, stream>>>(counts, row_start, cursor);
    fill_kernel<<<dim3(EE/256), blk, 0, stream>>>(dst, cursor, perm);
    // attention (finalize folded into combine)
    logits_max_kernel<<<dim3(EH/256), blk, 0, stream>>>(qkb, rab, src, dst, lg, mEnc);
    exp_den_kernel<<<dim3(EH/256), blk, 0, stream>>>(dst, mEnc, lg, den);
    // fused r_ij GEMM + attn-finalize + x_ij epilogue
    combine_mfma<<<dim3(EE/128), blk, 0, stream>>>(
        embb, wT[7], bC[7], lg, den, nee, dst, ewt, osb, odb, otb);
    // atomic-free gather (applies xv)
    gather_kernel<<<dim3(NN), dim3(128), 0, stream>>>(
        row_start, perm, src, osb, odb, otb, xv, ev, h_in, mu_in, h_out, mu_out);
    // vector branch: merged vq|vk0
    mm_bf16<0,0,0><<<dim3(3*NN/128, 2), blk, 0, stream>>>(mu_out, wT[8], bC[8], w12, nullptr, nullptr, 256, 128);
    wdot_fused<<<dim3(EE/128), blk, 0, stream>>>(
        w12, ev, src, dst, wT[10], bC[10], embb, fup, df);
}

// Round 6
// 416.357 us; speedup vs baseline: 3.7626x; 1.1057x over previous
//
#include <hip/hip_runtime.h>
#include <math.h>

#define NN 16384
#define EE 131072
#define ZZ 128
#define HH 8

typedef short bf16x8 __attribute__((ext_vector_type(8)));
typedef float f32x4 __attribute__((ext_vector_type(4)));
typedef unsigned short ushort4v __attribute__((ext_vector_type(4)));
typedef unsigned short ushort8v __attribute__((ext_vector_type(8)));

__device__ __forceinline__ float silu_f(float x) { return x / (1.0f + __expf(-x)); }

__device__ __forceinline__ unsigned short f2bf(float x) {
    unsigned u = __float_as_uint(x);
    unsigned r = (u >> 16) & 1u;
    u += 0x7fffu + r;
    return (unsigned short)(u >> 16);
}
__device__ __forceinline__ float bf2f(unsigned short x) {
    return __uint_as_float(((unsigned)x) << 16);
}

__device__ __forceinline__ f32x4 mfma16(bf16x8 a, bf16x8 b, f32x4 c) {
    return __builtin_amdgcn_mfma_f32_16x16x32_bf16(a, b, c, 0, 0, 0);
}

// stage a [128 x 128] bf16 tile (rows = output cols) from pre-transposed Wt
__device__ __forceinline__ void stageB(const unsigned short* Wt, char* lB, int t) {
    const uint4* Wg = (const uint4*)Wt;
#pragma unroll
    for (int i = 0; i < 8; ++i) {
        const int cid = t + i * 256;
        const int n = cid >> 4, c16 = cid & 15;
        *(uint4*)(lB + ((n * 256 + c16 * 16) ^ ((n & 7) << 4))) = Wg[cid];
    }
}

// ---- weight prep: W [128 x P] f32 -> Wt [P x 128] bf16 (transposed) ----
struct WPrep {
    const float* w[13];
    int P[13];
    int tile0[14];
};

__global__ __launch_bounds__(128) void prep_weights(WPrep wp, unsigned short* wt) {
    int b = blockIdx.x, wi = 0;
    while (b >= wp.tile0[wi + 1]) ++wi;
    const int cg = (b - wp.tile0[wi]) * 128;
    const float* w = wp.w[wi];
    unsigned short* o = wt + (size_t)wp.tile0[wi] * 16384;
    const int P = wp.P[wi];
    const int t = threadIdx.x;
    for (int k0 = 0; k0 < 128; k0 += 8) {
        ushort8v v;
#pragma unroll
        for (int j = 0; j < 8; ++j) v[j] = f2bf(w[(size_t)(k0 + j) * P + cg + t]);
        *(ushort8v*)(o + (size_t)(cg + t) * 128 + k0) = v;
    }
}

struct BPrep {
    const float* b[13];
    int off[14];
};

__global__ __launch_bounds__(256) void prep_bias(BPrep bp, float* bcat) {
    const int idx = blockIdx.x * 256 + threadIdx.x;
    if (idx >= 2432) return;
    int wi = 0;
    while (idx >= bp.off[wi + 1]) ++wi;
    bcat[idx] = bp.b[wi] ? bp.b[wi][idx - bp.off[wi]] : 0.f;
}

// ---- bf16 MFMA GEMM: C[M x P] = act(A[M x 128] @ Wt^T + bias), bf16 out ----
template <int ACT, int INBF, int DUMP>
__global__ __launch_bounds__(256, 2) void mm_bf16(
    const void* __restrict__ Av, const unsigned short* __restrict__ Wt,
    const float* __restrict__ bias, unsigned short* __restrict__ C,
    const unsigned short* __restrict__ aux, unsigned short* __restrict__ dumpA,
    int P, int As)
{
    __shared__ uint4 lA4[2048];
    __shared__ uint4 lB4[2048];
    char* lA = (char*)lA4;
    char* lB = (char*)lB4;
    const int t = threadIdx.x;
    const size_t row0 = (size_t)blockIdx.x * 128;
    const int cg = blockIdx.y * 128;
    if (INBF) {
        const uint4* Ag = (const uint4*)((const unsigned short*)Av + row0 * As);
        const int rs = As >> 3;
#pragma unroll
        for (int i = 0; i < 8; ++i) {
            const int chunk = t + i * 256;
            const int r = chunk >> 4, c16 = chunk & 15;
            *(uint4*)(lA + ((r * 256 + c16 * 16) ^ ((r & 7) << 4))) = Ag[r * rs + c16];
        }
    } else {
        const float4* Ag = (const float4*)((const float*)Av + row0 * As);
        const int rs = As >> 2;
#pragma unroll
        for (int i = 0; i < 16; ++i) {
            const int f4 = t + i * 256;
            const int r = f4 >> 5, c4 = f4 & 31;
            const float4 v = Ag[r * rs + c4];
            ushort4v bb;
            bb.x = f2bf(v.x); bb.y = f2bf(v.y); bb.z = f2bf(v.z); bb.w = f2bf(v.w);
            *(ushort4v*)(lA + ((r * 256 + c4 * 8) ^ ((r & 7) << 4))) = bb;
        }
    }
    stageB(Wt + (size_t)cg * 128, lB, t);
    __syncthreads();
    if (DUMP) {
#pragma unroll
        for (int i = 0; i < 8; ++i) {
            const int ch = t + i * 256;
            const int row = ch >> 4, cpos = ch & 15;
            const uint4 v = *(const uint4*)(lA + ((row * 256 + cpos * 16) ^ ((row & 7) << 4)));
            *(uint4*)(dumpA + (row0 + row) * 128 + cpos * 8) = v;
        }
    }
    const int lane = t & 63, wid = t >> 6;
    const int rbase = (wid >> 1) * 64, cbase = (wid & 1) * 64;
    const int lr = lane & 15, lgp = lane >> 4;
    f32x4 acc[4][4];
#pragma unroll
    for (int i = 0; i < 4; ++i)
#pragma unroll
        for (int j = 0; j < 4; ++j) acc[i][j] = (f32x4){0.f, 0.f, 0.f, 0.f};
#pragma unroll
    for (int ks = 0; ks < 4; ++ks) {
        bf16x8 av[4], bv[4];
#pragma unroll
        for (int mt = 0; mt < 4; ++mt) {
            const int r = rbase + mt * 16 + lr;
            av[mt] = *(const bf16x8*)(lA + ((r * 256 + ks * 64 + lgp * 16) ^ ((r & 7) << 4)));
        }
#pragma unroll
        for (int nt = 0; nt < 4; ++nt) {
            const int c = cbase + nt * 16 + lr;
            bv[nt] = *(const bf16x8*)(lB + ((c * 256 + ks * 64 + lgp * 16) ^ ((c & 7) << 4)));
        }
#pragma unroll
        for (int mt = 0; mt < 4; ++mt)
#pragma unroll
            for (int nt = 0; nt < 4; ++nt)
                acc[mt][nt] = mfma16(av[mt], bv[nt], acc[mt][nt]);
    }
    // epilogue: repack through LDS (lB free) -> coalesced stores
    __syncthreads();
#pragma unroll
    for (int nt = 0; nt < 4; ++nt) {
        const int col = cbase + nt * 16 + lr;
        const int gcol = cg + col;
        const float b = bias[gcol];
#pragma unroll
        for (int mt = 0; mt < 4; ++mt) {
#pragma unroll
            for (int j = 0; j < 4; ++j) {
                const int row = rbase + mt * 16 + lgp * 4 + j;
                float v = acc[mt][nt][j] + b;
                if (ACT == 1) v = silu_f(v);
                if (ACT == 2) v = v * bf2f(aux[(row0 + row) * (size_t)P + gcol]);
                *(unsigned short*)(lB + ((row * 256 + col * 2) ^ ((row & 7) << 4))) = f2bf(v);
            }
        }
    }
    __syncthreads();
#pragma unroll
    for (int i = 0; i < 8; ++i) {
        const int ch = t + i * 256;
        const int row = ch >> 4, cpos = ch & 15;
        const uint4 v = *(const uint4*)(lB + ((row * 256 + cpos * 16) ^ ((row & 7) << 4)));
        *(uint4*)(C + (row0 + row) * (size_t)P + cg + cpos * 8) = v;
    }
}

// ---- per-node CSR attention: attnw[e][h] = softmax * sqrt(deg)/sqrt(Z) * cut ----
// one wave per node; lane = edge_slot(8) x head(8); online softmax via shfl.
__global__ __launch_bounds__(256) void attn_kernel(
    const int* __restrict__ row_start, const int* __restrict__ perm,
    const int* __restrict__ src, const unsigned short* __restrict__ qkb,
    const unsigned short* __restrict__ rab, const float* __restrict__ ewt,
    float* __restrict__ attnw)
{
    const int t = threadIdx.x;
    const int n = blockIdx.x * 4 + (t >> 6);
    const int lane = t & 63;
    const int el = lane >> 3, h = lane & 7;
    const int beg = row_start[n], end = row_start[n + 1];
    if (beg == end) return;
    const ushort8v q0 = *(const ushort8v*)(qkb + (size_t)n * 256 + h * 16);
    const ushort8v q1 = *(const ushort8v*)(qkb + (size_t)n * 256 + h * 16 + 8);
    float m = -1e30f, den = 0.f;
    for (int i0 = beg; i0 < end; i0 += 8) {
        const int i = i0 + el;
        const bool valid = i < end;
        const int e = perm[valid ? i : beg];
        const int s = src[e];
        const ushort8v k0 = *(const ushort8v*)(qkb + (size_t)s * 256 + 128 + h * 16);
        const ushort8v k1 = *(const ushort8v*)(qkb + (size_t)s * 256 + 128 + h * 16 + 8);
        const ushort8v r0 = *(const ushort8v*)(rab + (size_t)e * 128 + h * 16);
        const ushort8v r1 = *(const ushort8v*)(rab + (size_t)e * 128 + h * 16 + 8);
        float lgv = 0.f;
#pragma unroll
        for (int j = 0; j < 8; ++j) lgv += bf2f(q0[j]) * bf2f(k0[j]) * bf2f(r0[j]);
#pragma unroll
        for (int j = 0; j < 8; ++j) lgv += bf2f(q1[j]) * bf2f(k1[j]) * bf2f(r1[j]);
        if (!valid) lgv = -1e30f;
        else attnw[(size_t)e * 8 + h] = lgv;   // stash raw logit
        float cm = lgv;
        cm = fmaxf(cm, __shfl_xor(cm, 8));
        cm = fmaxf(cm, __shfl_xor(cm, 16));
        cm = fmaxf(cm, __shfl_xor(cm, 32));
        const float nm = fmaxf(m, cm);
        float ex = valid ? __expf(lgv - nm) : 0.f;
        float cd = ex;
        cd += __shfl_xor(cd, 8);
        cd += __shfl_xor(cd, 16);
        cd += __shfl_xor(cd, 32);
        den = den * __expf(m - nm) + cd;
        m = nm;
    }
    const float sc = sqrtf((float)(end - beg)) * 0.08838834764831845f / den;
    for (int i0 = beg; i0 < end; i0 += 8) {
        const int i = i0 + el;
        if (i >= end) continue;
        const int e = perm[i];
        const float w = ewt[e];
        const float cut = (w < 5.0f) ? 0.5f * (cosf(w * 0.62831853071795864f) + 1.0f) : 0.0f;
        const float lgv = attnw[(size_t)e * 8 + h];
        attnw[(size_t)e * 8 + h] = __expf(lgv - m) * sc * cut;
    }
}

// ---- fused r_ij MFMA GEMM + x_ij epilogue ----
// B from global (L2-resident weights); swapped mfma operands -> lane holds
// 4 consecutive output cols -> direct 8B packed bf16 stores (no repack).
__global__ __launch_bounds__(256, 4) void combine_mfma(
    const unsigned short* __restrict__ embb, const unsigned short* __restrict__ Wt_re,
    const float* __restrict__ bre, const float* __restrict__ attnw,
    unsigned short* __restrict__ osb, unsigned short* __restrict__ odb,
    unsigned short* __restrict__ otb)
{
    __shared__ uint4 lA4[2048];
    __shared__ float attnS[128 * 8];
    char* lA = (char*)lA4;
    const int t = threadIdx.x;
    const size_t e0 = (size_t)blockIdx.x * 128;
    {
        const uint4* Ag = (const uint4*)(embb + e0 * 128);
#pragma unroll
        for (int i = 0; i < 8; ++i) {
            const int chunk = t + i * 256;
            const int r = chunk >> 4, c16 = chunk & 15;
            *(uint4*)(lA + ((r * 256 + c16 * 16) ^ ((r & 7) << 4))) = Ag[chunk];
        }
    }
    ((float4*)attnS)[t] = ((const float4*)(attnw + e0 * 8))[t];
    __syncthreads();
    const int lane = t & 63, wid = t >> 6;
    const int rbase = (wid >> 1) * 64, cbase = (wid & 1) * 64;
    const int lr = lane & 15, lgp = lane >> 4;
    unsigned short* bufs[3] = {osb, odb, otb};
    for (int cg3 = 0; cg3 < 3; ++cg3) {
        const unsigned short* Wp = Wt_re + (size_t)cg3 * 16384;
        f32x4 acc[4][4];
#pragma unroll
        for (int i = 0; i < 4; ++i)
#pragma unroll
            for (int j = 0; j < 4; ++j) acc[i][j] = (f32x4){0.f, 0.f, 0.f, 0.f};
#pragma unroll
        for (int ks = 0; ks < 4; ++ks) {
            bf16x8 av[4], bv[4];
#pragma unroll
            for (int mt = 0; mt < 4; ++mt) {
                const int r = rbase + mt * 16 + lr;
                av[mt] = *(const bf16x8*)(lA + ((r * 256 + ks * 64 + lgp * 16) ^ ((r & 7) << 4)));
            }
#pragma unroll
            for (int nt = 0; nt < 4; ++nt)
                bv[nt] = *(const bf16x8*)(Wp + (size_t)(cbase + nt * 16 + lr) * 128 + ks * 32 + lgp * 8);
#pragma unroll
            for (int mt = 0; mt < 4; ++mt)
#pragma unroll
                for (int nt = 0; nt < 4; ++nt)
                    acc[mt][nt] = mfma16(bv[nt], av[mt], acc[mt][nt]);  // swapped: D[c][r]
        }
        unsigned short* buf = bufs[cg3];
        const int cgo = cg3 * 128;
#pragma unroll
        for (int mt = 0; mt < 4; ++mt) {
            const int row = rbase + mt * 16 + lr;
            const float* aS = attnS + row * 8;
#pragma unroll
            for (int nt = 0; nt < 4; ++nt) {
                const int col0 = cbase + nt * 16 + lgp * 4;
                const int gcol = cgo + col0;
                const float coef = aS[gcol / 48];
                const float4 b4 = *(const float4*)(bre + gcol);
                ushort4v st;
                st.x = f2bf((acc[mt][nt][0] + b4.x) * coef);
                st.y = f2bf((acc[mt][nt][1] + b4.y) * coef);
                st.z = f2bf((acc[mt][nt][2] + b4.z) * coef);
                st.w = f2bf((acc[mt][nt][3] + b4.w) * coef);
                *(ushort4v*)(buf + (e0 + row) * 128 + col0) = st;
            }
        }
    }
}

// ---- fused (wd + w_dot GEMM + tanh/df), swapped operands, float4 df stores ----
__global__ __launch_bounds__(256, 3) void wdot_fused(
    const unsigned short* __restrict__ w12, const float* __restrict__ ev,
    const int* __restrict__ src, const int* __restrict__ dst,
    const unsigned short* __restrict__ Wt_lin, const float* __restrict__ bl,
    const unsigned short* __restrict__ embb, const unsigned short* __restrict__ fup,
    float* __restrict__ df)
{
    __shared__ uint4 lA4[2048];
    char* lA = (char*)lA4;
    const int t = threadIdx.x;
    const size_t e0 = (size_t)blockIdx.x * 128;
#pragma unroll
    for (int i = 0; i < 8; ++i) {
        const int chunk = t + i * 256;
        const int r = chunk >> 4, c8 = chunk & 15;
        const size_t e = e0 + r;
        const int s = src[e], d = dst[e];
        const float e0v = ev[e * 3 + 0], e1v = ev[e * 3 + 1], e2v = ev[e * 3 + 2];
        const ushort8v a0 = *(const ushort8v*)(w12 + ((size_t)d * 3 + 0) * 256 + c8 * 8);
        const ushort8v a1 = *(const ushort8v*)(w12 + ((size_t)d * 3 + 1) * 256 + c8 * 8);
        const ushort8v a2 = *(const ushort8v*)(w12 + ((size_t)d * 3 + 2) * 256 + c8 * 8);
        const ushort8v c0 = *(const ushort8v*)(w12 + ((size_t)s * 3 + 0) * 256 + 128 + c8 * 8);
        const ushort8v c1 = *(const ushort8v*)(w12 + ((size_t)s * 3 + 1) * 256 + 128 + c8 * 8);
        const ushort8v c2 = *(const ushort8v*)(w12 + ((size_t)s * 3 + 2) * 256 + 128 + c8 * 8);
        ushort8v o;
#pragma unroll
        for (int j = 0; j < 8; ++j) {
            const float av = e0v * bf2f(a0[j]) + e1v * bf2f(a1[j]) + e2v * bf2f(a2[j]);
            const float bv = e0v * bf2f(c0[j]) + e1v * bf2f(c1[j]) + e2v * bf2f(c2[j]);
            o[j] = f2bf(av * bv);
        }
        *(ushort8v*)(lA + ((r * 256 + c8 * 16) ^ ((r & 7) << 4))) = o;
    }
    __syncthreads();
    const int lane = t & 63, wid = t >> 6;
    const int rbase = (wid >> 1) * 64, cbase = (wid & 1) * 64;
    const int lr = lane & 15, lgp = lane >> 4;
    f32x4 acc[4][4];
#pragma unroll
    for (int i = 0; i < 4; ++i)
#pragma unroll
        for (int j = 0; j < 4; ++j) acc[i][j] = (f32x4){0.f, 0.f, 0.f, 0.f};
#pragma unroll
    for (int ks = 0; ks < 4; ++ks) {
        bf16x8 av[4], bv[4];
#pragma unroll
        for (int mt = 0; mt < 4; ++mt) {
            const int r = rbase + mt * 16 + lr;
            av[mt] = *(const bf16x8*)(lA + ((r * 256 + ks * 64 + lgp * 16) ^ ((r & 7) << 4)));
        }
#pragma unroll
        for (int nt = 0; nt < 4; ++nt)
            bv[nt] = *(const bf16x8*)(Wt_lin + (size_t)(cbase + nt * 16 + lr) * 128 + ks * 32 + lgp * 8);
#pragma unroll
        for (int mt = 0; mt < 4; ++mt)
#pragma unroll
            for (int nt = 0; nt < 4; ++nt)
                acc[mt][nt] = mfma16(bv[nt], av[mt], acc[mt][nt]);  // swapped
    }
#pragma unroll
    for (int mt = 0; mt < 4; ++mt) {
        const int row = rbase + mt * 16 + lr;
#pragma unroll
        for (int nt = 0; nt < 4; ++nt) {
            const int col0 = cbase + nt * 16 + lgp * 4;
            const float4 b4 = *(const float4*)(bl + col0);
            const size_t base = (e0 + row) * 128 + col0;
            const ushort4v em = *(const ushort4v*)(embb + base);
            const ushort4v fu = *(const ushort4v*)(fup + base);
            float4 o;
            o.x = bf2f(em.x) + bf2f(fu.x) * tanhf(acc[mt][nt][0] + b4.x);
            o.y = bf2f(em.y) + bf2f(fu.y) * tanhf(acc[mt][nt][1] + b4.y);
            o.z = bf2f(em.z) + bf2f(fu.z) * tanhf(acc[mt][nt][2] + b4.z);
            o.w = bf2f(em.w) + bf2f(fu.w) * tanhf(acc[mt][nt][3] + b4.w);
            *(float4*)(df + base) = o;
        }
    }
}

// ---- CSR build ----
__global__ __launch_bounds__(256) void hist_kernel(const int* __restrict__ dst, int* __restrict__ counts) {
    const int e = blockIdx.x * 256 + threadIdx.x;
    atomicAdd(&counts[dst[e]], 1);
}

__global__ __launch_bounds__(256) void scan_kernel(const int* __restrict__ counts,
                                                   int* __restrict__ row_start,
                                                   int* __restrict__ cursor) {
    __shared__ int part[256];
    const int t = threadIdx.x;
    const int base = t * 64;
    int local[64];
    int s = 0;
#pragma unroll
    for (int i = 0; i < 64; ++i) { local[i] = s; s += counts[base + i]; }
    part[t] = s;
    __syncthreads();
    for (int off = 1; off < 256; off <<= 1) {
        int v = (t >= off) ? part[t - off] : 0;
        __syncthreads();
        part[t] += v;
        __syncthreads();
    }
    const int prev = (t == 0) ? 0 : part[t - 1];
#pragma unroll
    for (int i = 0; i < 64; ++i) {
        const int v = prev + local[i];
        row_start[base + i] = v;
        cursor[base + i] = v;
    }
    if (t == 255) row_start[NN] = prev + s;
}

__global__ __launch_bounds__(256) void fill_kernel(const int* __restrict__ dst,
                                                   int* __restrict__ cursor,
                                                   int* __restrict__ perm) {
    const int e = blockIdx.x * 256 + threadIdx.x;
    const int p = atomicAdd(&cursor[dst[e]], 1);
    perm[p] = e;
}

// ---- gather per dst node (applies xv = x3*val3 factor); 2 nodes/block ----
__global__ __launch_bounds__(256) void gather_kernel(
    const int* __restrict__ row_start, const int* __restrict__ perm,
    const int* __restrict__ src, const unsigned short* __restrict__ osb,
    const unsigned short* __restrict__ odb, const unsigned short* __restrict__ otb,
    const unsigned short* __restrict__ xv, const float* __restrict__ ev,
    const float* __restrict__ h_in, const float* __restrict__ mu_in,
    float* __restrict__ h_out, float* __restrict__ mu_out)
{
    const int n = blockIdx.x * 2 + (threadIdx.x >> 7);
    const int t = threadIdx.x & 127;
    const int beg = row_start[n], end = row_start[n + 1];
    float hacc = h_in[(size_t)n * 128 + t];
    float m0 = mu_in[(size_t)n * 384 + t];
    float m1 = mu_in[(size_t)n * 384 + 128 + t];
    float m2 = mu_in[(size_t)n * 384 + 256 + t];
    for (int i = beg; i < end; ++i) {
        const int e = perm[i];
        const int s = src[e];
        const float e0 = ev[e * 3 + 0], e1 = ev[e * 3 + 1], e2 = ev[e * 3 + 2];
        const unsigned short* xp = xv + (size_t)s * 384 + t;
        const float osv = bf2f(osb[(size_t)e * 128 + t]) * bf2f(xp[0]);
        const float odv = bf2f(odb[(size_t)e * 128 + t]) * bf2f(xp[128]);
        const float otv = bf2f(otb[(size_t)e * 128 + t]) * bf2f(xp[256]);
        const float* msp = mu_in + (size_t)s * 384 + t;
        hacc += osv;
        m0 += odv * e0 + otv * msp[0];
        m1 += odv * e1 + otv * msp[128];
        m2 += odv * e2 + otv * msp[256];
    }
    h_out[(size_t)n * 128 + t] = hacc;
    mu_out[(size_t)n * 384 + t] = m0;
    mu_out[(size_t)n * 384 + 128 + t] = m1;
    mu_out[(size_t)n * 384 + 256 + t] = m2;
}

extern "C" void kernel_launch(void* const* d_in, const int* in_sizes, int n_in,
                              void* d_out, int out_size, void* d_ws, size_t ws_size,
                              hipStream_t stream) {
    const int* eidx = (const int*)d_in[0];
    const int* src = eidx;
    const int* dst = eidx + EE;
    const float* h_in  = (const float*)d_in[1];
    const float* mu_in = (const float*)d_in[2];
    const float* ev    = (const float*)d_in[3];
    const float* emb   = (const float*)d_in[4];
    const float* ewt   = (const float*)d_in[5];
    const float* W_q   = (const float*)d_in[7];  const float* b_q   = (const float*)d_in[8];
    const float* W_k   = (const float*)d_in[9];  const float* b_k   = (const float*)d_in[10];
    const float* W_gs1 = (const float*)d_in[11]; const float* b_gs1 = (const float*)d_in[12];
    const float* W_gs2 = (const float*)d_in[13]; const float* b_gs2 = (const float*)d_in[14];
    const float* W_gv1 = (const float*)d_in[15]; const float* b_gv1 = (const float*)d_in[16];
    const float* W_gv2 = (const float*)d_in[17]; const float* b_gv2 = (const float*)d_in[18];
    const float* W_phik= (const float*)d_in[19]; const float* b_phik= (const float*)d_in[20];
    const float* W_re  = (const float*)d_in[21]; const float* b_re  = (const float*)d_in[22];
    const float* W_vq  = (const float*)d_in[23];
    const float* W_vk0 = (const float*)d_in[24];
    const float* W_lin = (const float*)d_in[25]; const float* b_lin = (const float*)d_in[26];
    const float* W_eu1 = (const float*)d_in[27]; const float* b_eu1 = (const float*)d_in[28];
    const float* W_eu2 = (const float*)d_in[29]; const float* b_eu2 = (const float*)d_in[30];

    float* out    = (float*)d_out;
    float* h_out  = out;
    float* mu_out = out + (size_t)NN * ZZ;
    float* df     = out + (size_t)NN * ZZ * 4;

    const size_t NZ = (size_t)NN * ZZ, N3Z = (size_t)NN * 3 * ZZ, EZ = (size_t)EE * ZZ;
    const size_t EH = (size_t)EE * HH;
    char* p = (char*)d_ws;
    unsigned short* qkb   = (unsigned short*)p; p += NZ * 2 * 2;   // N x 256 (q|k)
    unsigned short* tmpn2 = (unsigned short*)p; p += NZ * 2 * 2;   // N x 256 (gs1|gv1)
    unsigned short* x3b   = (unsigned short*)p; p += N3Z * 2;      // N x 384
    unsigned short* xv    = (unsigned short*)p; p += N3Z * 2;      // N x 384
    unsigned short* w12   = (unsigned short*)p; p += N3Z * 2 * 2;  // 3N x 256 (w1|w2)
    unsigned short* embb  = (unsigned short*)p; p += EZ * 2;
    unsigned short* rab   = (unsigned short*)p; p += EZ * 2;
    unsigned short* tmpe  = (unsigned short*)p; p += EZ * 2;
    unsigned short* fup   = (unsigned short*)p; p += EZ * 2;
    unsigned short* osb   = (unsigned short*)p; p += EZ * 2;
    unsigned short* odb   = (unsigned short*)p; p += EZ * 2;
    unsigned short* otb   = (unsigned short*)p; p += EZ * 2;
    float* attnw          = (float*)p;          p += EH * 4;   // logits -> final coef
    unsigned short* wt    = (unsigned short*)p; p += 2432 * 128 * 2;
    float* bcat           = (float*)p;          p += 2432 * 4;
    int* counts           = (int*)p;            p += NN * 4;
    int* cursor           = (int*)p;            p += NN * 4;
    int* row_start        = (int*)p;            p += (NN + 1) * 4;
    int* perm             = (int*)p;            p += EE * 4;

    // pool order: q,k,gs1,gv1,gs2,gv2,phik,re,vq,vk0,lin,eu1,eu2
    const float* wsrc[13] = {W_q, W_k, W_gs1, W_gv1, W_gs2, W_gv2, W_phik,
                             W_re, W_vq, W_vk0, W_lin, W_eu1, W_eu2};
    const float* bsrc[13] = {b_q, b_k, b_gs1, b_gv1, b_gs2, b_gv2, b_phik,
                             b_re, nullptr, nullptr, b_lin, b_eu1, b_eu2};
    const int Ps[13] = {128, 128, 128, 128, 384, 384, 128, 384, 128, 128, 128, 128, 128};
    WPrep wp; BPrep bp;
    int tiles = 0;
    for (int i = 0; i < 13; ++i) {
        wp.w[i] = wsrc[i]; wp.P[i] = Ps[i]; wp.tile0[i] = tiles;
        bp.b[i] = bsrc[i]; bp.off[i] = tiles * 128;
        tiles += Ps[i] / 128;
    }
    wp.tile0[13] = tiles; bp.off[13] = tiles * 128;  // 19 tiles, 2432 cols
    unsigned short* wT[13]; const float* bC[13];
    for (int i = 0; i < 13; ++i) { wT[i] = wt + (size_t)wp.tile0[i] * 16384; bC[i] = bcat + bp.off[i]; }

    dim3 blk(256);
    prep_weights<<<dim3(tiles), dim3(128), 0, stream>>>(wp, wt);
    prep_bias<<<dim3(10), blk, 0, stream>>>(bp, bcat);
    // node-side GEMMs (merged)
    mm_bf16<0,0,0><<<dim3(NN/128, 2), blk, 0, stream>>>(h_in, wT[0], bC[0], qkb, nullptr, nullptr, 256, 128);
    mm_bf16<1,0,0><<<dim3(NN/128, 2), blk, 0, stream>>>(h_in, wT[2], bC[2], tmpn2, nullptr, nullptr, 256, 128);
    mm_bf16<0,1,0><<<dim3(NN/128, 3), blk, 0, stream>>>(tmpn2, wT[4], bC[4], x3b, nullptr, nullptr, 384, 256);
    mm_bf16<2,1,0><<<dim3(NN/128, 3), blk, 0, stream>>>(tmpn2 + 128, wT[5], bC[5], xv, x3b, nullptr, 384, 256);
    // edge-side: eu1 (dumps bf16 emb), eu2, phik
    mm_bf16<1,0,1><<<dim3(EE/128, 1), blk, 0, stream>>>(emb, wT[11], bC[11], tmpe, nullptr, embb, 128, 128);
    mm_bf16<0,1,0><<<dim3(EE/128, 1), blk, 0, stream>>>(tmpe, wT[12], bC[12], fup, nullptr, nullptr, 128, 128);
    mm_bf16<1,1,0><<<dim3(EE/128, 1), blk, 0, stream>>>(embb, wT[6], bC[6], rab, nullptr, nullptr, 128, 128);
    // CSR build
    hipMemsetAsync(counts, 0, NN * 4, stream);
    hist_kernel<<<dim3(EE/256), blk, 0, stream>>>(dst, counts);
    scan_kernel<<<dim3(1), blk, 0, stream>>>(counts, row_start, cursor);
    fill_kernel<<<dim3(EE/256), blk, 0, stream>>>(dst, cursor, perm);
    // per-node CSR attention -> final coef (softmax * sqrt(deg)/sqrt(Z) * cut)
    attn_kernel<<<dim3(NN/4), blk, 0, stream>>>(row_start, perm, src, qkb, rab, ewt, attnw);
    // fused r_ij GEMM + x_ij epilogue
    combine_mfma<<<dim3(EE/128), blk, 0, stream>>>(
        embb, wT[7], bC[7], attnw, osb, odb, otb);
    // atomic-free gather (applies xv)
    gather_kernel<<<dim3(NN/2), blk, 0, stream>>>(
        row_start, perm, src, osb, odb, otb, xv, ev, h_in, mu_in, h_out, mu_out);
    // vector branch: merged vq|vk0
    mm_bf16<0,0,0><<<dim3(3*NN/128, 2), blk, 0, stream>>>(mu_out, wT[8], bC[8], w12, nullptr, nullptr, 256, 128);
    wdot_fused<<<dim3(EE/128), blk, 0, stream>>>(
        w12, ev, src, dst, wT[10], bC[10], embb, fup, df);
}